// Round 1
// baseline (848.347 us; speedup 1.0000x reference)
//
#include <hip/hip_runtime.h>
#include <math.h>

#define BGR 8
#define NN 2048
#define KNN 4
#define INCH 16
#define HID 128
#define CL 64
#define NE 262144
#define NT (BGR*NN)   // 16384

// workspace layout (float offsets)
#define OFF_DEG   0            // 16384
#define OFF_AGG1  16384        // 262144
#define OFF_H1    278528       // 2097152
#define OFF_NBR   2375680      // 65536 (ints)
#define OFF_AGG2  2441216      // 2097152
#define OFF_H2    4538368      // 2097152
#define OFF_POOL  6635520      // 65536
#define OFF_SS    6701056      // 32768
#define OFF_TR    6733824      // 8
#define OFF_CA    6733832      // 512
#define OFF_SSUM  6734344      // 512
#define OFF_MS    6734856      // 8
// total 6734864 floats = ~27 MB

__global__ void k_zero(float* p, int n) {
  int i = blockIdx.x * 256 + threadIdx.x;
  if (i < n) p[i] = 0.f;
}

// in-degree histogram over original edges (also = adj.sum(1) for dmon)
__global__ void k_deg(const int* __restrict__ dst, float* __restrict__ deg) {
  int e = blockIdx.x * 256 + threadIdx.x;
  if (e < NE) atomicAdd(&deg[dst[e]], 1.0f);
}

// scatter x[src]*dis[src] into agg1[dst] (16 channels, linearity of GCN)
__global__ void k_scatter1(const int* __restrict__ src, const int* __restrict__ dst,
                           const float* __restrict__ x, const float* __restrict__ deg,
                           float* __restrict__ agg1) {
  int t = blockIdx.x * 256 + threadIdx.x;
  int e = t >> 4, c = t & 15;
  if (e >= NE) return;
  int s = src[e], d = dst[e];
  float ds = 1.0f / sqrtf(deg[s] + 1.0f);
  atomicAdd(&agg1[d * INCH + c], x[s * INCH + c] * ds);
}

// h1 = relu( ((agg1 + x*dis)*dis) @ W1 + b1 )
__global__ __launch_bounds__(128) void k_gemm1(const float* __restrict__ agg1,
    const float* __restrict__ x, const float* __restrict__ deg,
    const float* __restrict__ W1, const float* __restrict__ b1, float* __restrict__ h1) {
  __shared__ float a1[INCH];
  int n = blockIdx.x, j = threadIdx.x;
  if (j < INCH) {
    float dn = 1.0f / sqrtf(deg[n] + 1.0f);
    a1[j] = (agg1[n * INCH + j] + x[n * INCH + j] * dn) * dn;
  }
  __syncthreads();
  float acc = b1[j];
#pragma unroll
  for (int c = 0; c < INCH; c++) acc += a1[c] * W1[c * HID + j];
  h1[(size_t)n * HID + j] = fmaxf(acc, 0.f);
}

// kNN (k=4) per graph on h1[:, :3]; stable (distance, index) ordering like top_k
__global__ __launch_bounds__(128) void k_knn(const float* __restrict__ h1, int* __restrict__ nbr) {
  __shared__ float cx[NN], cy[NN], cz[NN];
  int g = blockIdx.y, tid = threadIdx.x;
  for (int i = tid; i < NN; i += 128) {
    const float* r = h1 + (size_t)(g * NN + i) * HID;
    cx[i] = r[0]; cy[i] = r[1]; cz[i] = r[2];
  }
  __syncthreads();
  int rrow = blockIdx.x * 128 + tid;
  float mx = cx[rrow], my = cy[rrow], mz = cz[rrow];
  float bd0 = 1e30f, bd1 = 1e30f, bd2 = 1e30f, bd3 = 1e30f;
  int bi0 = 0, bi1 = 0, bi2 = 0, bi3 = 0;
  for (int j = 0; j < NN; j++) {
    float dx = cx[j] - mx, dy = cy[j] - my, dz = cz[j] - mz;
    float d2 = dx * dx + dy * dy + dz * dz;
    if (j == rrow) continue;
    if (d2 < bd3) {
      if (d2 < bd2) {
        bd3 = bd2; bi3 = bi2;
        if (d2 < bd1) {
          bd2 = bd1; bi2 = bi1;
          if (d2 < bd0) { bd1 = bd0; bi1 = bi0; bd0 = d2; bi0 = j; }
          else { bd1 = d2; bi1 = j; }
        } else { bd2 = d2; bi2 = j; }
      } else { bd3 = d2; bi3 = j; }
    }
  }
  int base = (g * NN + rrow) * 4;
  nbr[base + 0] = g * NN + bi0; nbr[base + 1] = g * NN + bi1;
  nbr[base + 2] = g * NN + bi2; nbr[base + 3] = g * NN + bi3;
}

// agg2[n] = (h1[n] + sum_{4 nbrs} h1[nbr]) * (1/5)
__global__ void k_agg2(const float* __restrict__ h1, const int* __restrict__ nbr,
                       float* __restrict__ agg2) {
  int t = blockIdx.x * 256 + threadIdx.x;   // NT*HID threads
  int n = t >> 7, cc = t & 127;
  const int4 nb = ((const int4*)nbr)[n];
  const float dis = 1.0f / sqrtf(5.0f);
  const float nrm = dis * dis;
  float v = h1[(size_t)n * HID + cc]
          + h1[(size_t)nb.x * HID + cc] + h1[(size_t)nb.y * HID + cc]
          + h1[(size_t)nb.z * HID + cc] + h1[(size_t)nb.w * HID + cc];
  agg2[t] = v * nrm;
}

// h2 = relu(agg2 @ W2 + b2), tiled 64x128 output per block
__global__ __launch_bounds__(256) void k_gemm2(const float* __restrict__ A,
    const float* __restrict__ W2, const float* __restrict__ b2, float* __restrict__ h2) {
  __shared__ float At[64][17];
  __shared__ float Bt[16 * 128];
  int tid = threadIdx.x;
  int rbase = blockIdx.x * 64;
  int rg = tid >> 5;            // 0..7 -> rows rg*8..+8
  int cg = (tid & 31) * 4;      // cols
  float acc[8][4];
#pragma unroll
  for (int i = 0; i < 8; i++)
#pragma unroll
    for (int j = 0; j < 4; j++) acc[i][j] = 0.f;
  for (int k0 = 0; k0 < HID; k0 += 16) {
    {
      int r = tid >> 2;
      int kk = (tid & 3) * 4;
      float4 v = *(const float4*)&A[(size_t)(rbase + r) * HID + k0 + kk];
      At[r][kk] = v.x; At[r][kk + 1] = v.y; At[r][kk + 2] = v.z; At[r][kk + 3] = v.w;
    }
    {
      int kk = tid >> 5;
      int cc = (tid & 31) * 4;
      *(float4*)&Bt[kk * 128 + cc] = *(const float4*)&W2[(k0 + kk) * HID + cc];
      *(float4*)&Bt[(kk + 8) * 128 + cc] = *(const float4*)&W2[(k0 + kk + 8) * HID + cc];
    }
    __syncthreads();
#pragma unroll
    for (int kk = 0; kk < 16; kk++) {
      float4 bv = *(const float4*)&Bt[kk * 128 + cg];
#pragma unroll
      for (int i = 0; i < 8; i++) {
        float av = At[rg * 8 + i][kk];
        acc[i][0] += av * bv.x; acc[i][1] += av * bv.y;
        acc[i][2] += av * bv.z; acc[i][3] += av * bv.w;
      }
    }
    __syncthreads();
  }
#pragma unroll
  for (int i = 0; i < 8; i++) {
    int r = rbase + rg * 8 + i;
#pragma unroll
    for (int j = 0; j < 4; j++) {
      float v = acc[i][j] + b2[cg + j];
      h2[(size_t)r * HID + cg + j] = fmaxf(v, 0.f);
    }
  }
}

// s = softmax(h2 @ Wp + bp) over C=64, one wave per node, 16 nodes/block
__global__ __launch_bounds__(64) void k_s(const float* __restrict__ h2,
    const float* __restrict__ Wp, const float* __restrict__ bp, float* __restrict__ s_out) {
  __shared__ float wp[HID * CL];   // 32KB
  __shared__ float hrow[HID];
  int tid = threadIdx.x;
  for (int i = tid; i < HID * CL; i += 64) wp[i] = Wp[i];
  __syncthreads();
  for (int u = 0; u < 16; u++) {
    int n = blockIdx.x * 16 + u;
    hrow[tid] = h2[(size_t)n * HID + tid];
    hrow[tid + 64] = h2[(size_t)n * HID + tid + 64];
    __syncthreads();
    float acc = bp[tid];
#pragma unroll 8
    for (int k = 0; k < HID; k++) acc += hrow[k] * wp[k * CL + tid];
    float m = acc;
    for (int off = 32; off; off >>= 1) m = fmaxf(m, __shfl_xor(m, off, 64));
    float e = expf(acc - m);
    float sum = e;
    for (int off = 32; off; off >>= 1) sum += __shfl_xor(sum, off, 64);
    s_out[(size_t)n * CL + tid] = e / sum;
    __syncthreads();
  }
}

// per-graph: ssum[c]=sum_n s, ca[c]=sum_n s*deg, msum=sum_n deg
__global__ __launch_bounds__(256) void k_red1(const float* __restrict__ s,
    const float* __restrict__ deg, float* __restrict__ ca, float* __restrict__ ssum,
    float* __restrict__ msum) {
  __shared__ float red[256];
  int b = blockIdx.x, tid = threadIdx.x;
  int c = tid & 63, q = tid >> 6;
  float a_ss = 0, a_ca = 0, a_m = 0;
  for (int n = q; n < NN; n += 4) {
    float sv = s[((size_t)b * NN + n) * CL + c];
    float dv = deg[b * NN + n];
    a_ss += sv; a_ca += sv * dv;
    if (c == 0) a_m += dv;
  }
  red[tid] = a_ss; __syncthreads();
  if (q == 0) ssum[b * CL + c] = red[c] + red[64 + c] + red[128 + c] + red[192 + c];
  __syncthreads();
  red[tid] = a_ca; __syncthreads();
  if (q == 0) ca[b * CL + c] = red[c] + red[64 + c] + red[128 + c] + red[192 + c];
  __syncthreads();
  red[tid] = (c == 0) ? a_m : 0.f; __syncthreads();
  if (tid == 0) msum[b] = red[0] + red[64] + red[128] + red[192];
}

// ss[b] += s_tile^T s_tile  (128-node slices)
__global__ __launch_bounds__(256) void k_ss(const float* __restrict__ s, float* __restrict__ ss) {
  __shared__ float st[128 * 64];   // 32KB
  int b = blockIdx.y, sl = blockIdx.x, tid = threadIdx.x;
  const float* sp = s + ((size_t)b * NN + sl * 128) * CL;
  for (int i = tid; i < 128 * 64; i += 256) st[i] = sp[i];
  __syncthreads();
  int c = tid & 63, dg = (tid >> 6) * 16;
  float acc[16];
#pragma unroll
  for (int i = 0; i < 16; i++) acc[i] = 0.f;
  for (int n = 0; n < 128; n++) {
    float a = st[n * 64 + c];
#pragma unroll
    for (int i = 0; i < 16; i++) acc[i] += a * st[n * 64 + dg + i];
  }
  float* outp = ss + (size_t)b * CL * CL + c * CL + dg;
  for (int i = 0; i < 16; i++) atomicAdd(&outp[i], acc[i]);
}

// pool[b,c,f] += sum_n s[b,n,c]*h2[b,n,f]  (128-node slices, two 64-node subtiles)
__global__ __launch_bounds__(256) void k_pool(const float* __restrict__ s,
    const float* __restrict__ h2, float* __restrict__ pool) {
  __shared__ float st[64 * 64];    // 16KB
  __shared__ float ht[64 * 128];   // 32KB
  int b = blockIdx.y, sl = blockIdx.x, tid = threadIdx.x;
  int c = tid & 63, fg = (tid >> 6) * 32;
  float acc[32];
#pragma unroll
  for (int i = 0; i < 32; i++) acc[i] = 0.f;
  for (int half = 0; half < 2; half++) {
    int nb = sl * 128 + half * 64;
    const float* sp = s + ((size_t)b * NN + nb) * CL;
    const float* hp = h2 + ((size_t)b * NN + nb) * HID;
    __syncthreads();
    for (int i = tid; i < 64 * 64; i += 256) st[i] = sp[i];
    for (int i = tid; i < 64 * 128; i += 256) ht[i] = hp[i];
    __syncthreads();
    for (int n = 0; n < 64; n++) {
      float a = st[n * 64 + c];
#pragma unroll
      for (int i = 0; i < 32; i++) acc[i] += a * ht[n * 128 + fg + i];
    }
  }
  float* outp = pool + (size_t)b * CL * HID + c * HID + fg;
  for (int i = 0; i < 32; i++) atomicAdd(&outp[i], acc[i]);
}

// trace(s^T A s) per graph = sum over edges of dot(s[src], s[dst])
__global__ __launch_bounds__(256) void k_trace(const int* __restrict__ src,
    const int* __restrict__ dst, const float* __restrict__ s, float* __restrict__ tr) {
  __shared__ float bins[8];
  int tid = threadIdx.x;
  if (tid < 8) bins[tid] = 0.f;
  __syncthreads();
  int lane = tid & 63;
  int gw = blockIdx.x * 4 + (tid >> 6);     // 2048 waves
  for (int e = gw; e < NE; e += 2048) {
    int se = src[e], de = dst[e];
    float v = s[(size_t)se * CL + lane] * s[(size_t)de * CL + lane];
    for (int off = 32; off; off >>= 1) v += __shfl_xor(v, off, 64);
    if (lane == 0) atomicAdd(&bins[se >> 11], v);
  }
  __syncthreads();
  if (tid < 8) atomicAdd(&tr[tid], bins[tid]);
}

// selu then log_softmax over F=128; one row (b,c) per block
__global__ __launch_bounds__(128) void k_lsm(const float* __restrict__ pool, float* __restrict__ out) {
  __shared__ float r[2], r2[2];
  int row = blockIdx.x, tid = threadIdx.x;
  float v = pool[(size_t)row * HID + tid];
  const float scale = 1.0507009873554805f, alpha = 1.6732632423543772f;
  v = scale * (v > 0.f ? v : alpha * expm1f(v));
  float m = v;
  for (int off = 32; off; off >>= 1) m = fmaxf(m, __shfl_xor(m, off, 64));
  if ((tid & 63) == 0) r[tid >> 6] = m;
  __syncthreads();
  m = fmaxf(r[0], r[1]);
  float e = expf(v - m);
  float sum = e;
  for (int off = 32; off; off >>= 1) sum += __shfl_xor(sum, off, 64);
  if ((tid & 63) == 0) r2[tid >> 6] = sum;
  __syncthreads();
  sum = r2[0] + r2[1];
  out[(size_t)row * HID + tid] = v - m - logf(sum);
}

// final scalar: spectral + ortho + cluster (all means over graphs)
__global__ __launch_bounds__(256) void k_scalar(const float* __restrict__ ss,
    const float* __restrict__ ca, const float* __restrict__ ssum,
    const float* __restrict__ msum, const float* __restrict__ tr, float* __restrict__ outs) {
  __shared__ float red[256];
  int tid = threadIdx.x;
  float total = 0.f;
  for (int b = 0; b < BGR; b++) {
    float loc = 0.f;
    for (int i = tid; i < 4096; i += 256) { float v = ss[b * 4096 + i]; loc += v * v; }
    red[tid] = loc; __syncthreads();
    for (int s2 = 128; s2; s2 >>= 1) { if (tid < s2) red[tid] += red[tid + s2]; __syncthreads(); }
    float fro = sqrtf(red[0]);
    __syncthreads();
    loc = 0.f;
    for (int i = tid; i < 4096; i += 256) {
      float v = ss[b * 4096 + i] / fro - (((i % 65) == 0) ? 0.125f : 0.f);
      loc += v * v;
    }
    red[tid] = loc; __syncthreads();
    for (int s2 = 128; s2; s2 >>= 1) { if (tid < s2) red[tid] += red[tid + s2]; __syncthreads(); }
    float ortho_b = sqrtf(red[0]);
    __syncthreads();
    loc = 0.f;
    if (tid < 64) { float v = ca[b * 64 + tid]; loc = v * v; }
    red[tid] = loc; __syncthreads();
    for (int s2 = 128; s2; s2 >>= 1) { if (tid < s2) red[tid] += red[tid + s2]; __syncthreads(); }
    float caSq = red[0];
    __syncthreads();
    loc = 0.f;
    if (tid < 64) { float v = ssum[b * 64 + tid]; loc = v * v; }
    red[tid] = loc; __syncthreads();
    for (int s2 = 128; s2; s2 >>= 1) { if (tid < s2) red[tid] += red[tid + s2]; __syncthreads(); }
    float ssumSq = red[0];
    __syncthreads();
    float m2 = msum[b];                       // = 2*m
    float spectral_b = -(tr[b] - caSq / m2) / m2;
    float cluster_b = sqrtf(ssumSq) / 2048.0f * 8.0f - 1.0f;
    total += spectral_b + ortho_b + cluster_b;
  }
  if (tid == 0) outs[0] = total / 8.0f;
}

extern "C" void kernel_launch(void* const* d_in, const int* in_sizes, int n_in,
                              void* d_out, int out_size, void* d_ws, size_t ws_size,
                              hipStream_t stream) {
  (void)in_sizes; (void)n_in; (void)out_size; (void)ws_size;
  const float* x   = (const float*)d_in[0];
  const int* esrc  = (const int*)d_in[1];
  const int* edst  = (const int*)d_in[2];
  const float* W1  = (const float*)d_in[4];
  const float* b1  = (const float*)d_in[5];
  const float* W2  = (const float*)d_in[6];
  const float* b2  = (const float*)d_in[7];
  const float* Wp  = (const float*)d_in[8];
  const float* bp  = (const float*)d_in[9];
  float* out = (float*)d_out;
  float* ws  = (float*)d_ws;

  float* deg   = ws + OFF_DEG;
  float* agg1  = ws + OFF_AGG1;
  float* h1    = ws + OFF_H1;
  int*   nbr   = (int*)(ws + OFF_NBR);
  float* agg2  = ws + OFF_AGG2;
  float* h2    = ws + OFF_H2;
  float* pool  = ws + OFF_POOL;
  float* ssb   = ws + OFF_SS;
  float* tr    = ws + OFF_TR;
  float* ca    = ws + OFF_CA;
  float* ssum  = ws + OFF_SSUM;
  float* msum  = ws + OFF_MS;
  float* s_out = out + 65537;   // chunk 2: s [8,2048,64]

  k_zero<<<(278528 + 255) / 256, 256, 0, stream>>>(ws, 278528);            // deg+agg1
  k_zero<<<(98312 + 255) / 256, 256, 0, stream>>>(ws + OFF_POOL, 98312);   // pool+ss+tr
  k_deg<<<NE / 256, 256, 0, stream>>>(edst, deg);
  k_scatter1<<<NE * 16 / 256, 256, 0, stream>>>(esrc, edst, x, deg, agg1);
  k_gemm1<<<NT, 128, 0, stream>>>(agg1, x, deg, W1, b1, h1);
  k_knn<<<dim3(16, 8), 128, 0, stream>>>(h1, nbr);
  k_agg2<<<NT * HID / 256, 256, 0, stream>>>(h1, nbr, agg2);
  k_gemm2<<<NT / 64, 256, 0, stream>>>(agg2, W2, b2, h2);
  k_s<<<NT / 16, 64, 0, stream>>>(h2, Wp, bp, s_out);
  k_red1<<<BGR, 256, 0, stream>>>(s_out, deg, ca, ssum, msum);
  k_ss<<<dim3(16, 8), 256, 0, stream>>>(s_out, ssb);
  k_pool<<<dim3(16, 8), 256, 0, stream>>>(s_out, h2, pool);
  k_trace<<<512, 256, 0, stream>>>(esrc, edst, s_out, tr);
  k_lsm<<<512, 128, 0, stream>>>(pool, out);
  k_scalar<<<1, 256, 0, stream>>>(ssb, ca, ssum, msum, tr, out + 65536);
}

// Round 2
// 620.934 us; speedup vs baseline: 1.3662x; 1.3662x over previous
//
#include <hip/hip_runtime.h>
#include <math.h>

#define BGR 8
#define NN 2048
#define KNN 4
#define INCH 16
#define HID 128
#define CL 64
#define NE 262144
#define NT (BGR*NN)   // 16384

// workspace layout (float offsets)
#define OFF_DEG   0            // 16384
#define OFF_AGG1  16384        // 262144
#define OFF_H1    278528       // 2097152
#define OFF_NBR   2375680      // 65536 (ints)
#define OFF_AGG2  2441216      // 2097152
#define OFF_H2    4538368      // 2097152
#define OFF_POOL  6635520      // 65536
#define OFF_SS    6701056      // 32768
#define OFF_TR    6733824      // 8
#define OFF_CA    6733832      // 512
#define OFF_SSUM  6734344      // 512
#define OFF_MS    6734856      // 8
// total 6734864 floats = ~27 MB

__global__ void k_zero(float* p, int n) {
  int i = blockIdx.x * 256 + threadIdx.x;
  if (i < n) p[i] = 0.f;
}

// in-degree histogram over original edges (also = adj.sum(1) for dmon)
__global__ void k_deg(const int* __restrict__ dst, float* __restrict__ deg) {
  int e = blockIdx.x * 256 + threadIdx.x;
  if (e < NE) atomicAdd(&deg[dst[e]], 1.0f);
}

// scatter x[src]*dis[src] into agg1[dst] (16 channels, linearity of GCN)
__global__ void k_scatter1(const int* __restrict__ src, const int* __restrict__ dst,
                           const float* __restrict__ x, const float* __restrict__ deg,
                           float* __restrict__ agg1) {
  int t = blockIdx.x * 256 + threadIdx.x;
  int e = t >> 4, c = t & 15;
  if (e >= NE) return;
  int s = src[e], d = dst[e];
  float ds = 1.0f / sqrtf(deg[s] + 1.0f);
  atomicAdd(&agg1[d * INCH + c], x[s * INCH + c] * ds);
}

// h1 = relu( ((agg1 + x*dis)*dis) @ W1 + b1 )
__global__ __launch_bounds__(128) void k_gemm1(const float* __restrict__ agg1,
    const float* __restrict__ x, const float* __restrict__ deg,
    const float* __restrict__ W1, const float* __restrict__ b1, float* __restrict__ h1) {
  __shared__ float a1[INCH];
  int n = blockIdx.x, j = threadIdx.x;
  if (j < INCH) {
    float dn = 1.0f / sqrtf(deg[n] + 1.0f);
    a1[j] = (agg1[n * INCH + j] + x[n * INCH + j] * dn) * dn;
  }
  __syncthreads();
  float acc = b1[j];
#pragma unroll
  for (int c = 0; c < INCH; c++) acc += a1[c] * W1[c * HID + j];
  h1[(size_t)n * HID + j] = fmaxf(acc, 0.f);
}

// kNN k=4 per graph on h1[:, :3].
// One wave per 4 rows: 64 lanes scan strided candidates keeping branchless
// per-lane top-4, then 4 rounds of wave-wide lexicographic argmin-pop.
// Ordering matches jax.lax.top_k: ascending (d2, index).
__global__ __launch_bounds__(256) void k_knn(const float* __restrict__ h1, int* __restrict__ nbr) {
  __shared__ float cx[NN], cy[NN], cz[NN];   // 24KB
  int g = blockIdx.y, tid = threadIdx.x;
  for (int i = tid; i < NN; i += 256) {
    const float* r = h1 + (size_t)(g * NN + i) * HID;
    cx[i] = r[0]; cy[i] = r[1]; cz[i] = r[2];
  }
  __syncthreads();
  int wid = tid >> 6, lane = tid & 63;
  int row0 = blockIdx.x * 16 + wid * 4;
  float mx[4], my[4], mz[4];
#pragma unroll
  for (int r = 0; r < 4; r++) { mx[r] = cx[row0 + r]; my[r] = cy[row0 + r]; mz[r] = cz[row0 + r]; }
  float t0[4], t1[4], t2[4], t3[4];
  int   i0[4], i1[4], i2[4], i3[4];
#pragma unroll
  for (int r = 0; r < 4; r++) {
    t0[r] = t1[r] = t2[r] = t3[r] = 3e38f;
    i0[r] = i1[r] = i2[r] = i3[r] = 0x7fffffff;
  }
  for (int i = 0; i < 32; i++) {
    int j = i * 64 + lane;
    float px = cx[j], py = cy[j], pz = cz[j];
#pragma unroll
    for (int r = 0; r < 4; r++) {
      float dx = px - mx[r], dy = py - my[r], dz = pz - mz[r];
      float d2 = dx * dx + dy * dy + dz * dz;
      if (j == row0 + r) d2 = 3e38f;   // exclude self
      bool in3 = d2 < t3[r], in2 = d2 < t2[r], in1 = d2 < t1[r], in0 = d2 < t0[r];
      t3[r] = in2 ? t2[r] : (in3 ? d2 : t3[r]); i3[r] = in2 ? i2[r] : (in3 ? j : i3[r]);
      t2[r] = in1 ? t1[r] : (in2 ? d2 : t2[r]); i2[r] = in1 ? i1[r] : (in2 ? j : i2[r]);
      t1[r] = in0 ? t0[r] : (in1 ? d2 : t1[r]); i1[r] = in0 ? i0[r] : (in1 ? j : i1[r]);
      t0[r] = in0 ? d2 : t0[r];                 i0[r] = in0 ? j : i0[r];
    }
  }
#pragma unroll
  for (int r = 0; r < 4; r++) {
    float a0 = t0[r], a1 = t1[r], a2 = t2[r], a3 = t3[r];
    int   b0 = i0[r], b1 = i1[r], b2 = i2[r], b3 = i3[r];
    int p = 0;
    int r0 = 0, r1 = 0, r2 = 0, r3 = 0;
#pragma unroll
    for (int k = 0; k < 4; k++) {
      float cd = (p == 0) ? a0 : (p == 1) ? a1 : (p == 2) ? a2 : (p == 3) ? a3 : 3e38f;
      int   ci = (p == 0) ? b0 : (p == 1) ? b1 : (p == 2) ? b2 : (p == 3) ? b3 : 0x7fffffff;
      float wd = cd; int wi = ci;
#pragma unroll
      for (int off = 32; off; off >>= 1) {
        float od = __shfl_xor(wd, off, 64);
        int   oi = __shfl_xor(wi, off, 64);
        bool take = (od < wd) || (od == wd && oi < wi);
        wd = take ? od : wd; wi = take ? oi : wi;
      }
      if (k == 0) r0 = wi; else if (k == 1) r1 = wi; else if (k == 2) r2 = wi; else r3 = wi;
      if (ci == wi) p++;    // owner pops (indices unique)
    }
    if (lane == 0) {
      int node = g * NN + row0 + r;
      ((int4*)nbr)[node] = make_int4(g * NN + r0, g * NN + r1, g * NN + r2, g * NN + r3);
    }
  }
}

// agg2[n] = (h1[n] + sum_{4 nbrs} h1[nbr]) * (1/5)
__global__ void k_agg2(const float* __restrict__ h1, const int* __restrict__ nbr,
                       float* __restrict__ agg2) {
  int t = blockIdx.x * 256 + threadIdx.x;   // NT*HID threads
  int n = t >> 7, cc = t & 127;
  const int4 nb = ((const int4*)nbr)[n];
  const float nrm = 0.2f;
  float v = h1[(size_t)n * HID + cc]
          + h1[(size_t)nb.x * HID + cc] + h1[(size_t)nb.y * HID + cc]
          + h1[(size_t)nb.z * HID + cc] + h1[(size_t)nb.w * HID + cc];
  agg2[t] = v * nrm;
}

// h2 = relu(agg2 @ W2 + b2), tiled 64x128 output per block
__global__ __launch_bounds__(256) void k_gemm2(const float* __restrict__ A,
    const float* __restrict__ W2, const float* __restrict__ b2, float* __restrict__ h2) {
  __shared__ float At[64][17];
  __shared__ float Bt[16 * 128];
  int tid = threadIdx.x;
  int rbase = blockIdx.x * 64;
  int rg = tid >> 5;            // 0..7 -> rows rg*8..+8
  int cg = (tid & 31) * 4;      // cols
  float acc[8][4];
#pragma unroll
  for (int i = 0; i < 8; i++)
#pragma unroll
    for (int j = 0; j < 4; j++) acc[i][j] = 0.f;
  for (int k0 = 0; k0 < HID; k0 += 16) {
    {
      int r = tid >> 2;
      int kk = (tid & 3) * 4;
      float4 v = *(const float4*)&A[(size_t)(rbase + r) * HID + k0 + kk];
      At[r][kk] = v.x; At[r][kk + 1] = v.y; At[r][kk + 2] = v.z; At[r][kk + 3] = v.w;
    }
    {
      int kk = tid >> 5;
      int cc = (tid & 31) * 4;
      *(float4*)&Bt[kk * 128 + cc] = *(const float4*)&W2[(k0 + kk) * HID + cc];
      *(float4*)&Bt[(kk + 8) * 128 + cc] = *(const float4*)&W2[(k0 + kk + 8) * HID + cc];
    }
    __syncthreads();
#pragma unroll
    for (int kk = 0; kk < 16; kk++) {
      float4 bv = *(const float4*)&Bt[kk * 128 + cg];
#pragma unroll
      for (int i = 0; i < 8; i++) {
        float av = At[rg * 8 + i][kk];
        acc[i][0] += av * bv.x; acc[i][1] += av * bv.y;
        acc[i][2] += av * bv.z; acc[i][3] += av * bv.w;
      }
    }
    __syncthreads();
  }
#pragma unroll
  for (int i = 0; i < 8; i++) {
    int r = rbase + rg * 8 + i;
#pragma unroll
    for (int j = 0; j < 4; j++) {
      float v = acc[i][j] + b2[cg + j];
      h2[(size_t)r * HID + cg + j] = fmaxf(v, 0.f);
    }
  }
}

// s = softmax(h2 @ Wp + bp) over C=64; 4 waves/block share the Wp LDS copy,
// each wave handles 16 nodes (one node per iteration, one lane per cluster).
__global__ __launch_bounds__(256) void k_s(const float* __restrict__ h2,
    const float* __restrict__ Wp, const float* __restrict__ bp, float* __restrict__ s_out) {
  __shared__ float wp[HID * CL];     // 32KB
  __shared__ float hrow[4][HID];     // 2KB
  int tid = threadIdx.x, wid = tid >> 6, lane = tid & 63;
  {
    const float4* wp4 = (const float4*)Wp;
    float4* wps = (float4*)wp;
    for (int i = tid; i < HID * CL / 4; i += 256) wps[i] = wp4[i];
  }
  __syncthreads();
  float bpv = bp[lane];
  for (int u = 0; u < 16; u++) {
    int n = blockIdx.x * 64 + wid * 16 + u;
    hrow[wid][lane]      = h2[(size_t)n * HID + lane];
    hrow[wid][lane + 64] = h2[(size_t)n * HID + lane + 64];
    __syncthreads();
    float acc = bpv;
#pragma unroll 8
    for (int k = 0; k < HID; k++) acc += hrow[wid][k] * wp[k * CL + lane];
    float m = acc;
    for (int off = 32; off; off >>= 1) m = fmaxf(m, __shfl_xor(m, off, 64));
    float e = expf(acc - m);
    float sum = e;
    for (int off = 32; off; off >>= 1) sum += __shfl_xor(sum, off, 64);
    s_out[(size_t)n * CL + lane] = e / sum;
    __syncthreads();
  }
}

// per-graph: ssum[c]=sum_n s, ca[c]=sum_n s*deg, msum=sum_n deg
__global__ __launch_bounds__(256) void k_red1(const float* __restrict__ s,
    const float* __restrict__ deg, float* __restrict__ ca, float* __restrict__ ssum,
    float* __restrict__ msum) {
  __shared__ float red[256];
  int b = blockIdx.x, tid = threadIdx.x;
  int c = tid & 63, q = tid >> 6;
  float a_ss = 0, a_ca = 0, a_m = 0;
  for (int n = q; n < NN; n += 4) {
    float sv = s[((size_t)b * NN + n) * CL + c];
    float dv = deg[b * NN + n];
    a_ss += sv; a_ca += sv * dv;
    if (c == 0) a_m += dv;
  }
  red[tid] = a_ss; __syncthreads();
  if (q == 0) ssum[b * CL + c] = red[c] + red[64 + c] + red[128 + c] + red[192 + c];
  __syncthreads();
  red[tid] = a_ca; __syncthreads();
  if (q == 0) ca[b * CL + c] = red[c] + red[64 + c] + red[128 + c] + red[192 + c];
  __syncthreads();
  red[tid] = (c == 0) ? a_m : 0.f; __syncthreads();
  if (tid == 0) msum[b] = red[0] + red[64] + red[128] + red[192];
}

// ss[b] += s_tile^T s_tile  (128-node slices)
__global__ __launch_bounds__(256) void k_ss(const float* __restrict__ s, float* __restrict__ ss) {
  __shared__ float st[128 * 64];   // 32KB
  int b = blockIdx.y, sl = blockIdx.x, tid = threadIdx.x;
  const float* sp = s + ((size_t)b * NN + sl * 128) * CL;
  for (int i = tid; i < 128 * 64; i += 256) st[i] = sp[i];
  __syncthreads();
  int c = tid & 63, dg = (tid >> 6) * 16;
  float acc[16];
#pragma unroll
  for (int i = 0; i < 16; i++) acc[i] = 0.f;
  for (int n = 0; n < 128; n++) {
    float a = st[n * 64 + c];
#pragma unroll
    for (int i = 0; i < 16; i++) acc[i] += a * st[n * 64 + dg + i];
  }
  float* outp = ss + (size_t)b * CL * CL + c * CL + dg;
  for (int i = 0; i < 16; i++) atomicAdd(&outp[i], acc[i]);
}

// pool[b,c,f] += sum_n s[b,n,c]*h2[b,n,f]  (128-node slices, two 64-node subtiles)
__global__ __launch_bounds__(256) void k_pool(const float* __restrict__ s,
    const float* __restrict__ h2, float* __restrict__ pool) {
  __shared__ float st[64 * 64];    // 16KB
  __shared__ float ht[64 * 128];   // 32KB
  int b = blockIdx.y, sl = blockIdx.x, tid = threadIdx.x;
  int c = tid & 63, fg = (tid >> 6) * 32;
  float acc[32];
#pragma unroll
  for (int i = 0; i < 32; i++) acc[i] = 0.f;
  for (int half = 0; half < 2; half++) {
    int nb = sl * 128 + half * 64;
    const float* sp = s + ((size_t)b * NN + nb) * CL;
    const float* hp = h2 + ((size_t)b * NN + nb) * HID;
    __syncthreads();
    for (int i = tid; i < 64 * 64; i += 256) st[i] = sp[i];
    for (int i = tid; i < 64 * 128; i += 256) ht[i] = hp[i];
    __syncthreads();
    for (int n = 0; n < 64; n++) {
      float a = st[n * 64 + c];
#pragma unroll
      for (int i = 0; i < 32; i++) acc[i] += a * ht[n * 128 + fg + i];
    }
  }
  float* outp = pool + (size_t)b * CL * HID + c * HID + fg;
  for (int i = 0; i < 32; i++) atomicAdd(&outp[i], acc[i]);
}

// trace(s^T A s) per graph = sum over edges of dot(s[src], s[dst])
__global__ __launch_bounds__(256) void k_trace(const int* __restrict__ src,
    const int* __restrict__ dst, const float* __restrict__ s, float* __restrict__ tr) {
  __shared__ float bins[8];
  int tid = threadIdx.x;
  if (tid < 8) bins[tid] = 0.f;
  __syncthreads();
  int lane = tid & 63;
  int gw = blockIdx.x * 4 + (tid >> 6);     // 2048 waves
  for (int e = gw; e < NE; e += 2048) {
    int se = src[e], de = dst[e];
    float v = s[(size_t)se * CL + lane] * s[(size_t)de * CL + lane];
    for (int off = 32; off; off >>= 1) v += __shfl_xor(v, off, 64);
    if (lane == 0) atomicAdd(&bins[se >> 11], v);
  }
  __syncthreads();
  if (tid < 8) atomicAdd(&tr[tid], bins[tid]);
}

// selu then log_softmax over F=128; one row (b,c) per block
__global__ __launch_bounds__(128) void k_lsm(const float* __restrict__ pool, float* __restrict__ out) {
  __shared__ float r[2], r2[2];
  int row = blockIdx.x, tid = threadIdx.x;
  float v = pool[(size_t)row * HID + tid];
  const float scale = 1.0507009873554805f, alpha = 1.6732632423543772f;
  v = scale * (v > 0.f ? v : alpha * expm1f(v));
  float m = v;
  for (int off = 32; off; off >>= 1) m = fmaxf(m, __shfl_xor(m, off, 64));
  if ((tid & 63) == 0) r[tid >> 6] = m;
  __syncthreads();
  m = fmaxf(r[0], r[1]);
  float e = expf(v - m);
  float sum = e;
  for (int off = 32; off; off >>= 1) sum += __shfl_xor(sum, off, 64);
  if ((tid & 63) == 0) r2[tid >> 6] = sum;
  __syncthreads();
  sum = r2[0] + r2[1];
  out[(size_t)row * HID + tid] = v - m - logf(sum);
}

// final scalar: spectral + ortho + cluster (all means over graphs)
__global__ __launch_bounds__(256) void k_scalar(const float* __restrict__ ss,
    const float* __restrict__ ca, const float* __restrict__ ssum,
    const float* __restrict__ msum, const float* __restrict__ tr, float* __restrict__ outs) {
  __shared__ float red[256];
  int tid = threadIdx.x;
  float total = 0.f;
  for (int b = 0; b < BGR; b++) {
    float loc = 0.f;
    for (int i = tid; i < 4096; i += 256) { float v = ss[b * 4096 + i]; loc += v * v; }
    red[tid] = loc; __syncthreads();
    for (int s2 = 128; s2; s2 >>= 1) { if (tid < s2) red[tid] += red[tid + s2]; __syncthreads(); }
    float fro = sqrtf(red[0]);
    __syncthreads();
    loc = 0.f;
    for (int i = tid; i < 4096; i += 256) {
      float v = ss[b * 4096 + i] / fro - (((i % 65) == 0) ? 0.125f : 0.f);
      loc += v * v;
    }
    red[tid] = loc; __syncthreads();
    for (int s2 = 128; s2; s2 >>= 1) { if (tid < s2) red[tid] += red[tid + s2]; __syncthreads(); }
    float ortho_b = sqrtf(red[0]);
    __syncthreads();
    loc = 0.f;
    if (tid < 64) { float v = ca[b * 64 + tid]; loc = v * v; }
    red[tid] = loc; __syncthreads();
    for (int s2 = 128; s2; s2 >>= 1) { if (tid < s2) red[tid] += red[tid + s2]; __syncthreads(); }
    float caSq = red[0];
    __syncthreads();
    loc = 0.f;
    if (tid < 64) { float v = ssum[b * 64 + tid]; loc = v * v; }
    red[tid] = loc; __syncthreads();
    for (int s2 = 128; s2; s2 >>= 1) { if (tid < s2) red[tid] += red[tid + s2]; __syncthreads(); }
    float ssumSq = red[0];
    __syncthreads();
    float m2 = msum[b];                       // = 2*m
    float spectral_b = -(tr[b] - caSq / m2) / m2;
    float cluster_b = sqrtf(ssumSq) / 2048.0f * 8.0f - 1.0f;
    total += spectral_b + ortho_b + cluster_b;
  }
  if (tid == 0) outs[0] = total / 8.0f;
}

extern "C" void kernel_launch(void* const* d_in, const int* in_sizes, int n_in,
                              void* d_out, int out_size, void* d_ws, size_t ws_size,
                              hipStream_t stream) {
  (void)in_sizes; (void)n_in; (void)out_size; (void)ws_size;
  const float* x   = (const float*)d_in[0];
  const int* esrc  = (const int*)d_in[1];
  const int* edst  = (const int*)d_in[2];
  const float* W1  = (const float*)d_in[4];
  const float* b1  = (const float*)d_in[5];
  const float* W2  = (const float*)d_in[6];
  const float* b2  = (const float*)d_in[7];
  const float* Wp  = (const float*)d_in[8];
  const float* bp  = (const float*)d_in[9];
  float* out = (float*)d_out;
  float* ws  = (float*)d_ws;

  float* deg   = ws + OFF_DEG;
  float* agg1  = ws + OFF_AGG1;
  float* h1    = ws + OFF_H1;
  int*   nbr   = (int*)(ws + OFF_NBR);
  float* agg2  = ws + OFF_AGG2;
  float* h2    = ws + OFF_H2;
  float* pool  = ws + OFF_POOL;
  float* ssb   = ws + OFF_SS;
  float* tr    = ws + OFF_TR;
  float* ca    = ws + OFF_CA;
  float* ssum  = ws + OFF_SSUM;
  float* msum  = ws + OFF_MS;
  float* s_out = out + 65537;   // chunk 2: s [8,2048,64]

  k_zero<<<(278528 + 255) / 256, 256, 0, stream>>>(ws, 278528);            // deg+agg1
  k_zero<<<(98312 + 255) / 256, 256, 0, stream>>>(ws + OFF_POOL, 98312);   // pool+ss+tr
  k_deg<<<NE / 256, 256, 0, stream>>>(edst, deg);
  k_scatter1<<<NE * 16 / 256, 256, 0, stream>>>(esrc, edst, x, deg, agg1);
  k_gemm1<<<NT, 128, 0, stream>>>(agg1, x, deg, W1, b1, h1);
  k_knn<<<dim3(128, 8), 256, 0, stream>>>(h1, nbr);
  k_agg2<<<NT * HID / 256, 256, 0, stream>>>(h1, nbr, agg2);
  k_gemm2<<<NT / 64, 256, 0, stream>>>(agg2, W2, b2, h2);
  k_s<<<NT / 64, 256, 0, stream>>>(h2, Wp, bp, s_out);
  k_red1<<<BGR, 256, 0, stream>>>(s_out, deg, ca, ssum, msum);
  k_ss<<<dim3(16, 8), 256, 0, stream>>>(s_out, ssb);
  k_pool<<<dim3(16, 8), 256, 0, stream>>>(s_out, h2, pool);
  k_trace<<<512, 256, 0, stream>>>(esrc, edst, s_out, tr);
  k_lsm<<<512, 128, 0, stream>>>(pool, out);
  k_scalar<<<1, 256, 0, stream>>>(ssb, ca, ssum, msum, tr, out + 65536);
}

// Round 3
// 439.264 us; speedup vs baseline: 1.9313x; 1.4136x over previous
//
#include <hip/hip_runtime.h>
#include <math.h>

#define BGR 8
#define NN 2048
#define KNN 4
#define INCH 16
#define HID 128
#define CL 64
#define NE 262144
#define NT (BGR*NN)   // 16384

// workspace layout (float offsets)
#define OFF_DEG   0            // 16384
#define OFF_AGG1  16384        // 262144
#define OFF_H1    278528       // 2097152
#define OFF_NBR   2375680      // 65536 (ints)
#define OFF_AGG2  2441216      // 2097152
#define OFF_H2    4538368      // 2097152
#define OFF_POOL  6635520      // 65536
#define OFF_SS    6701056      // 32768
#define OFF_TR    6733824      // 8
#define OFF_CA    6733832      // 512
#define OFF_SSUM  6734344      // 512
#define OFF_MS    6734856      // 8
// total 6734864 floats = ~27 MB

__global__ void k_zero(float* p, int n) {
  int i = blockIdx.x * 256 + threadIdx.x;
  if (i < n) p[i] = 0.f;
}

// in-degree histogram over original edges (also = adj.sum(1) for dmon)
__global__ void k_deg(const int* __restrict__ dst, float* __restrict__ deg) {
  int e = blockIdx.x * 256 + threadIdx.x;
  if (e < NE) atomicAdd(&deg[dst[e]], 1.0f);
}

// scatter x[src]*dis[src] into agg1[dst] (16 channels, linearity of GCN)
__global__ void k_scatter1(const int* __restrict__ src, const int* __restrict__ dst,
                           const float* __restrict__ x, const float* __restrict__ deg,
                           float* __restrict__ agg1) {
  int t = blockIdx.x * 256 + threadIdx.x;
  int e = t >> 4, c = t & 15;
  if (e >= NE) return;
  int s = src[e], d = dst[e];
  float ds = 1.0f / sqrtf(deg[s] + 1.0f);
  atomicAdd(&agg1[d * INCH + c], x[s * INCH + c] * ds);
}

// h1 = relu( ((agg1 + x*dis)*dis) @ W1 + b1 )
__global__ __launch_bounds__(128) void k_gemm1(const float* __restrict__ agg1,
    const float* __restrict__ x, const float* __restrict__ deg,
    const float* __restrict__ W1, const float* __restrict__ b1, float* __restrict__ h1) {
  __shared__ float a1[INCH];
  int n = blockIdx.x, j = threadIdx.x;
  if (j < INCH) {
    float dn = 1.0f / sqrtf(deg[n] + 1.0f);
    a1[j] = (agg1[n * INCH + j] + x[n * INCH + j] * dn) * dn;
  }
  __syncthreads();
  float acc = b1[j];
#pragma unroll
  for (int c = 0; c < INCH; c++) acc += a1[c] * W1[c * HID + j];
  h1[(size_t)n * HID + j] = fmaxf(acc, 0.f);
}

// kNN k=4 per graph on h1[:, :3].
// One wave per 4 rows: 64 lanes scan strided candidates keeping branchless
// per-lane top-4, then 4 rounds of wave-wide lexicographic argmin-pop.
// Ordering matches jax.lax.top_k: ascending (d2, index).
__global__ __launch_bounds__(256) void k_knn(const float* __restrict__ h1, int* __restrict__ nbr) {
  __shared__ float cx[NN], cy[NN], cz[NN];   // 24KB
  int g = blockIdx.y, tid = threadIdx.x;
  for (int i = tid; i < NN; i += 256) {
    const float* r = h1 + (size_t)(g * NN + i) * HID;
    cx[i] = r[0]; cy[i] = r[1]; cz[i] = r[2];
  }
  __syncthreads();
  int wid = tid >> 6, lane = tid & 63;
  int row0 = blockIdx.x * 16 + wid * 4;
  float mx[4], my[4], mz[4];
#pragma unroll
  for (int r = 0; r < 4; r++) { mx[r] = cx[row0 + r]; my[r] = cy[row0 + r]; mz[r] = cz[row0 + r]; }
  float t0[4], t1[4], t2[4], t3[4];
  int   i0[4], i1[4], i2[4], i3[4];
#pragma unroll
  for (int r = 0; r < 4; r++) {
    t0[r] = t1[r] = t2[r] = t3[r] = 3e38f;
    i0[r] = i1[r] = i2[r] = i3[r] = 0x7fffffff;
  }
  for (int i = 0; i < 32; i++) {
    int j = i * 64 + lane;
    float px = cx[j], py = cy[j], pz = cz[j];
#pragma unroll
    for (int r = 0; r < 4; r++) {
      float dx = px - mx[r], dy = py - my[r], dz = pz - mz[r];
      float d2 = dx * dx + dy * dy + dz * dz;
      if (j == row0 + r) d2 = 3e38f;   // exclude self
      bool in3 = d2 < t3[r], in2 = d2 < t2[r], in1 = d2 < t1[r], in0 = d2 < t0[r];
      t3[r] = in2 ? t2[r] : (in3 ? d2 : t3[r]); i3[r] = in2 ? i2[r] : (in3 ? j : i3[r]);
      t2[r] = in1 ? t1[r] : (in2 ? d2 : t2[r]); i2[r] = in1 ? i1[r] : (in2 ? j : i2[r]);
      t1[r] = in0 ? t0[r] : (in1 ? d2 : t1[r]); i1[r] = in0 ? i0[r] : (in1 ? j : i1[r]);
      t0[r] = in0 ? d2 : t0[r];                 i0[r] = in0 ? j : i0[r];
    }
  }
#pragma unroll
  for (int r = 0; r < 4; r++) {
    float a0 = t0[r], a1 = t1[r], a2 = t2[r], a3 = t3[r];
    int   b0 = i0[r], b1 = i1[r], b2 = i2[r], b3 = i3[r];
    int p = 0;
    int r0 = 0, r1 = 0, r2 = 0, r3 = 0;
#pragma unroll
    for (int k = 0; k < 4; k++) {
      float cd = (p == 0) ? a0 : (p == 1) ? a1 : (p == 2) ? a2 : (p == 3) ? a3 : 3e38f;
      int   ci = (p == 0) ? b0 : (p == 1) ? b1 : (p == 2) ? b2 : (p == 3) ? b3 : 0x7fffffff;
      float wd = cd; int wi = ci;
#pragma unroll
      for (int off = 32; off; off >>= 1) {
        float od = __shfl_xor(wd, off, 64);
        int   oi = __shfl_xor(wi, off, 64);
        bool take = (od < wd) || (od == wd && oi < wi);
        wd = take ? od : wd; wi = take ? oi : wi;
      }
      if (k == 0) r0 = wi; else if (k == 1) r1 = wi; else if (k == 2) r2 = wi; else r3 = wi;
      if (ci == wi) p++;    // owner pops (indices unique)
    }
    if (lane == 0) {
      int node = g * NN + row0 + r;
      ((int4*)nbr)[node] = make_int4(g * NN + r0, g * NN + r1, g * NN + r2, g * NN + r3);
    }
  }
}

// agg2[n] = (h1[n] + sum_{4 nbrs} h1[nbr]) * (1/5)
__global__ void k_agg2(const float* __restrict__ h1, const int* __restrict__ nbr,
                       float* __restrict__ agg2) {
  int t = blockIdx.x * 256 + threadIdx.x;   // NT*HID threads
  int n = t >> 7, cc = t & 127;
  const int4 nb = ((const int4*)nbr)[n];
  const float nrm = 0.2f;
  float v = h1[(size_t)n * HID + cc]
          + h1[(size_t)nb.x * HID + cc] + h1[(size_t)nb.y * HID + cc]
          + h1[(size_t)nb.z * HID + cc] + h1[(size_t)nb.w * HID + cc];
  agg2[t] = v * nrm;
}

// h2 = relu(agg2 @ W2 + b2), tiled 64x128 output per block
__global__ __launch_bounds__(256) void k_gemm2(const float* __restrict__ A,
    const float* __restrict__ W2, const float* __restrict__ b2, float* __restrict__ h2) {
  __shared__ float At[64][17];
  __shared__ float Bt[16 * 128];
  int tid = threadIdx.x;
  int rbase = blockIdx.x * 64;
  int rg = tid >> 5;            // 0..7 -> rows rg*8..+8
  int cg = (tid & 31) * 4;      // cols
  float acc[8][4];
#pragma unroll
  for (int i = 0; i < 8; i++)
#pragma unroll
    for (int j = 0; j < 4; j++) acc[i][j] = 0.f;
  for (int k0 = 0; k0 < HID; k0 += 16) {
    {
      int r = tid >> 2;
      int kk = (tid & 3) * 4;
      float4 v = *(const float4*)&A[(size_t)(rbase + r) * HID + k0 + kk];
      At[r][kk] = v.x; At[r][kk + 1] = v.y; At[r][kk + 2] = v.z; At[r][kk + 3] = v.w;
    }
    {
      int kk = tid >> 5;
      int cc = (tid & 31) * 4;
      *(float4*)&Bt[kk * 128 + cc] = *(const float4*)&W2[(k0 + kk) * HID + cc];
      *(float4*)&Bt[(kk + 8) * 128 + cc] = *(const float4*)&W2[(k0 + kk + 8) * HID + cc];
    }
    __syncthreads();
#pragma unroll
    for (int kk = 0; kk < 16; kk++) {
      float4 bv = *(const float4*)&Bt[kk * 128 + cg];
#pragma unroll
      for (int i = 0; i < 8; i++) {
        float av = At[rg * 8 + i][kk];
        acc[i][0] += av * bv.x; acc[i][1] += av * bv.y;
        acc[i][2] += av * bv.z; acc[i][3] += av * bv.w;
      }
    }
    __syncthreads();
  }
#pragma unroll
  for (int i = 0; i < 8; i++) {
    int r = rbase + rg * 8 + i;
#pragma unroll
    for (int j = 0; j < 4; j++) {
      float v = acc[i][j] + b2[cg + j];
      h2[(size_t)r * HID + cg + j] = fmaxf(v, 0.f);
    }
  }
}

// s = softmax(h2 @ Wp + bp) over C=64; 4 waves/block share the Wp LDS copy,
// each wave handles 16 nodes (one node per iteration, one lane per cluster).
__global__ __launch_bounds__(256) void k_s(const float* __restrict__ h2,
    const float* __restrict__ Wp, const float* __restrict__ bp, float* __restrict__ s_out) {
  __shared__ float wp[HID * CL];     // 32KB
  __shared__ float hrow[4][HID];     // 2KB
  int tid = threadIdx.x, wid = tid >> 6, lane = tid & 63;
  {
    const float4* wp4 = (const float4*)Wp;
    float4* wps = (float4*)wp;
    for (int i = tid; i < HID * CL / 4; i += 256) wps[i] = wp4[i];
  }
  __syncthreads();
  float bpv = bp[lane];
  for (int u = 0; u < 16; u++) {
    int n = blockIdx.x * 64 + wid * 16 + u;
    hrow[wid][lane]      = h2[(size_t)n * HID + lane];
    hrow[wid][lane + 64] = h2[(size_t)n * HID + lane + 64];
    __syncthreads();
    float acc = bpv;
#pragma unroll 8
    for (int k = 0; k < HID; k++) acc += hrow[wid][k] * wp[k * CL + lane];
    float m = acc;
    for (int off = 32; off; off >>= 1) m = fmaxf(m, __shfl_xor(m, off, 64));
    float e = expf(acc - m);
    float sum = e;
    for (int off = 32; off; off >>= 1) sum += __shfl_xor(sum, off, 64);
    s_out[(size_t)n * CL + lane] = e / sum;
    __syncthreads();
  }
}

// per-graph partials: ssum[c]+=s, ca[c]+=s*deg, msum+=deg
// grid (32 slices of 64 nodes, 8 graphs) — atomic-combined
__global__ __launch_bounds__(256) void k_red1(const float* __restrict__ s,
    const float* __restrict__ deg, float* __restrict__ ca, float* __restrict__ ssum,
    float* __restrict__ msum) {
  __shared__ float red[256];
  int b = blockIdx.y, sl = blockIdx.x, tid = threadIdx.x;
  int c = tid & 63, q = tid >> 6;
  float a_ss = 0, a_ca = 0, a_m = 0;
  int n0 = sl * 64;
  for (int n = n0 + q; n < n0 + 64; n += 4) {
    float sv = s[((size_t)b * NN + n) * CL + c];
    float dv = deg[b * NN + n];
    a_ss += sv; a_ca += sv * dv;
    if (c == 0) a_m += dv;
  }
  red[tid] = a_ss; __syncthreads();
  if (q == 0) atomicAdd(&ssum[b * CL + c], red[c] + red[64 + c] + red[128 + c] + red[192 + c]);
  __syncthreads();
  red[tid] = a_ca; __syncthreads();
  if (q == 0) atomicAdd(&ca[b * CL + c], red[c] + red[64 + c] + red[128 + c] + red[192 + c]);
  __syncthreads();
  red[tid] = (c == 0) ? a_m : 0.f; __syncthreads();
  if (tid == 0) atomicAdd(&msum[b], red[0] + red[64] + red[128] + red[192]);
}

// ss[b] += s_tile^T s_tile  (128-node slices)
__global__ __launch_bounds__(256) void k_ss(const float* __restrict__ s, float* __restrict__ ss) {
  __shared__ float st[128 * 64];   // 32KB
  int b = blockIdx.y, sl = blockIdx.x, tid = threadIdx.x;
  const float* sp = s + ((size_t)b * NN + sl * 128) * CL;
  for (int i = tid; i < 128 * 64; i += 256) st[i] = sp[i];
  __syncthreads();
  int c = tid & 63, dg = (tid >> 6) * 16;
  float acc[16];
#pragma unroll
  for (int i = 0; i < 16; i++) acc[i] = 0.f;
  for (int n = 0; n < 128; n++) {
    float a = st[n * 64 + c];
#pragma unroll
    for (int i = 0; i < 16; i++) acc[i] += a * st[n * 64 + dg + i];
  }
  float* outp = ss + (size_t)b * CL * CL + c * CL + dg;
  for (int i = 0; i < 16; i++) atomicAdd(&outp[i], acc[i]);
}

// pool[b,c,f] += sum_n s[b,n,c]*h2[b,n,f]  (128-node slices, two 64-node subtiles)
__global__ __launch_bounds__(256) void k_pool(const float* __restrict__ s,
    const float* __restrict__ h2, float* __restrict__ pool) {
  __shared__ float st[64 * 64];    // 16KB
  __shared__ float ht[64 * 128];   // 32KB
  int b = blockIdx.y, sl = blockIdx.x, tid = threadIdx.x;
  int c = tid & 63, fg = (tid >> 6) * 32;
  float acc[32];
#pragma unroll
  for (int i = 0; i < 32; i++) acc[i] = 0.f;
  for (int half = 0; half < 2; half++) {
    int nb = sl * 128 + half * 64;
    const float* sp = s + ((size_t)b * NN + nb) * CL;
    const float* hp = h2 + ((size_t)b * NN + nb) * HID;
    __syncthreads();
    for (int i = tid; i < 64 * 64; i += 256) st[i] = sp[i];
    for (int i = tid; i < 64 * 128; i += 256) ht[i] = hp[i];
    __syncthreads();
    for (int n = 0; n < 64; n++) {
      float a = st[n * 64 + c];
#pragma unroll
      for (int i = 0; i < 32; i++) acc[i] += a * ht[n * 128 + fg + i];
    }
  }
  float* outp = pool + (size_t)b * CL * HID + c * HID + fg;
  for (int i = 0; i < 32; i++) atomicAdd(&outp[i], acc[i]);
}

// trace(s^T A s) per graph = sum over edges of dot(s[src], s[dst])
__global__ __launch_bounds__(256) void k_trace(const int* __restrict__ src,
    const int* __restrict__ dst, const float* __restrict__ s, float* __restrict__ tr) {
  __shared__ float bins[8];
  int tid = threadIdx.x;
  if (tid < 8) bins[tid] = 0.f;
  __syncthreads();
  int lane = tid & 63;
  int gw = blockIdx.x * 4 + (tid >> 6);     // 2048 waves
  for (int e = gw; e < NE; e += 2048) {
    int se = src[e], de = dst[e];
    float v = s[(size_t)se * CL + lane] * s[(size_t)de * CL + lane];
    for (int off = 32; off; off >>= 1) v += __shfl_xor(v, off, 64);
    if (lane == 0) atomicAdd(&bins[se >> 11], v);
  }
  __syncthreads();
  if (tid < 8) atomicAdd(&tr[tid], bins[tid]);
}

// selu then log_softmax over F=128; one row (b,c) per block
__global__ __launch_bounds__(128) void k_lsm(const float* __restrict__ pool, float* __restrict__ out) {
  __shared__ float r[2], r2[2];
  int row = blockIdx.x, tid = threadIdx.x;
  float v = pool[(size_t)row * HID + tid];
  const float scale = 1.0507009873554805f, alpha = 1.6732632423543772f;
  v = scale * (v > 0.f ? v : alpha * expm1f(v));
  float m = v;
  for (int off = 32; off; off >>= 1) m = fmaxf(m, __shfl_xor(m, off, 64));
  if ((tid & 63) == 0) r[tid >> 6] = m;
  __syncthreads();
  m = fmaxf(r[0], r[1]);
  float e = expf(v - m);
  float sum = e;
  for (int off = 32; off; off >>= 1) sum += __shfl_xor(sum, off, 64);
  if ((tid & 63) == 0) r2[tid >> 6] = sum;
  __syncthreads();
  sum = r2[0] + r2[1];
  out[(size_t)row * HID + tid] = v - m - logf(sum);
}

// per-graph scalar: spectral + ortho + cluster, atomic mean into outs[0]
__global__ __launch_bounds__(256) void k_scalar(const float* __restrict__ ss,
    const float* __restrict__ ca, const float* __restrict__ ssum,
    const float* __restrict__ msum, const float* __restrict__ tr, float* __restrict__ outs) {
  __shared__ float red[256];
  int tid = threadIdx.x, b = blockIdx.x;
  float loc = 0.f;
  for (int i = tid; i < 4096; i += 256) { float v = ss[b * 4096 + i]; loc += v * v; }
  red[tid] = loc; __syncthreads();
  for (int s2 = 128; s2; s2 >>= 1) { if (tid < s2) red[tid] += red[tid + s2]; __syncthreads(); }
  float fro = sqrtf(red[0]);
  __syncthreads();
  loc = 0.f;
  for (int i = tid; i < 4096; i += 256) {
    float v = ss[b * 4096 + i] / fro - (((i % 65) == 0) ? 0.125f : 0.f);
    loc += v * v;
  }
  red[tid] = loc; __syncthreads();
  for (int s2 = 128; s2; s2 >>= 1) { if (tid < s2) red[tid] += red[tid + s2]; __syncthreads(); }
  float ortho_b = sqrtf(red[0]);
  __syncthreads();
  loc = 0.f;
  if (tid < 64) { float v = ca[b * 64 + tid]; loc = v * v; }
  red[tid] = loc; __syncthreads();
  for (int s2 = 128; s2; s2 >>= 1) { if (tid < s2) red[tid] += red[tid + s2]; __syncthreads(); }
  float caSq = red[0];
  __syncthreads();
  loc = 0.f;
  if (tid < 64) { float v = ssum[b * 64 + tid]; loc = v * v; }
  red[tid] = loc; __syncthreads();
  for (int s2 = 128; s2; s2 >>= 1) { if (tid < s2) red[tid] += red[tid + s2]; __syncthreads(); }
  float ssumSq = red[0];
  __syncthreads();
  if (tid == 0) {
    float m2 = msum[b];                       // = 2*m
    float spectral_b = -(tr[b] - caSq / m2) / m2;
    float cluster_b = sqrtf(ssumSq) / 2048.0f * 8.0f - 1.0f;
    atomicAdd(&outs[0], (spectral_b + ortho_b + cluster_b) * 0.125f);
  }
}

extern "C" void kernel_launch(void* const* d_in, const int* in_sizes, int n_in,
                              void* d_out, int out_size, void* d_ws, size_t ws_size,
                              hipStream_t stream) {
  (void)in_sizes; (void)n_in; (void)out_size; (void)ws_size;
  const float* x   = (const float*)d_in[0];
  const int* esrc  = (const int*)d_in[1];
  const int* edst  = (const int*)d_in[2];
  const float* W1  = (const float*)d_in[4];
  const float* b1  = (const float*)d_in[5];
  const float* W2  = (const float*)d_in[6];
  const float* b2  = (const float*)d_in[7];
  const float* Wp  = (const float*)d_in[8];
  const float* bp  = (const float*)d_in[9];
  float* out = (float*)d_out;
  float* ws  = (float*)d_ws;

  float* deg   = ws + OFF_DEG;
  float* agg1  = ws + OFF_AGG1;
  float* h1    = ws + OFF_H1;
  int*   nbr   = (int*)(ws + OFF_NBR);
  float* agg2  = ws + OFF_AGG2;
  float* h2    = ws + OFF_H2;
  float* pool  = ws + OFF_POOL;
  float* ssb   = ws + OFF_SS;
  float* tr    = ws + OFF_TR;
  float* ca    = ws + OFF_CA;
  float* ssum  = ws + OFF_SSUM;
  float* msum  = ws + OFF_MS;
  float* s_out = out + 65537;   // chunk 2: s [8,2048,64]

  k_zero<<<(278528 + 255) / 256, 256, 0, stream>>>(ws, 278528);             // deg+agg1
  k_zero<<<(99344 + 255) / 256, 256, 0, stream>>>(ws + OFF_POOL, 99344);    // pool+ss+tr+ca+ssum+msum
  k_zero<<<1, 256, 0, stream>>>(out + 65536, 1);                            // loss accumulator
  k_deg<<<NE / 256, 256, 0, stream>>>(edst, deg);
  k_scatter1<<<NE * 16 / 256, 256, 0, stream>>>(esrc, edst, x, deg, agg1);
  k_gemm1<<<NT, 128, 0, stream>>>(agg1, x, deg, W1, b1, h1);
  k_knn<<<dim3(128, 8), 256, 0, stream>>>(h1, nbr);
  k_agg2<<<NT * HID / 256, 256, 0, stream>>>(h1, nbr, agg2);
  k_gemm2<<<NT / 64, 256, 0, stream>>>(agg2, W2, b2, h2);
  k_s<<<NT / 64, 256, 0, stream>>>(h2, Wp, bp, s_out);
  k_red1<<<dim3(32, BGR), 256, 0, stream>>>(s_out, deg, ca, ssum, msum);
  k_ss<<<dim3(16, 8), 256, 0, stream>>>(s_out, ssb);
  k_pool<<<dim3(16, 8), 256, 0, stream>>>(s_out, h2, pool);
  k_trace<<<512, 256, 0, stream>>>(esrc, edst, s_out, tr);
  k_lsm<<<512, 128, 0, stream>>>(pool, out);
  k_scalar<<<BGR, 256, 0, stream>>>(ssb, ca, ssum, msum, tr, out + 65536);
}

// Round 4
// 435.984 us; speedup vs baseline: 1.9458x; 1.0075x over previous
//
#include <hip/hip_runtime.h>
#include <math.h>

#define BGR 8
#define NN 2048
#define KNN 4
#define INCH 16
#define HID 128
#define CL 64
#define NE 262144
#define NT (BGR*NN)   // 16384

// workspace layout (float offsets)
#define OFF_DEG   0            // 16384
#define OFF_AGG1  16384        // 262144
#define OFF_H1    278528       // 2097152
#define OFF_NBR   2375680      // 65536 (ints)
#define OFF_AGG2  2441216      // 2097152
#define OFF_H2    4538368      // 2097152
#define OFF_POOL  6635520      // 65536
#define OFF_SS    6701056      // 32768
#define OFF_TR    6733824      // 8
#define OFF_CA    6733832      // 512
#define OFF_SSUM  6734344      // 512
#define OFF_MS    6734856      // 8
// total 6734864 floats = ~27 MB

__global__ void k_zero(float* p, int n) {
  int i = blockIdx.x * 256 + threadIdx.x;
  if (i < n) p[i] = 0.f;
}

// in-degree histogram over original edges (also = adj.sum(1) for dmon)
__global__ void k_deg(const int* __restrict__ dst, float* __restrict__ deg) {
  int e = blockIdx.x * 256 + threadIdx.x;
  if (e < NE) atomicAdd(&deg[dst[e]], 1.0f);
}

// scatter x[src]*dis[src] into agg1[dst] (16 channels, linearity of GCN)
__global__ void k_scatter1(const int* __restrict__ src, const int* __restrict__ dst,
                           const float* __restrict__ x, const float* __restrict__ deg,
                           float* __restrict__ agg1) {
  int t = blockIdx.x * 256 + threadIdx.x;
  int e = t >> 4, c = t & 15;
  if (e >= NE) return;
  int s = src[e], d = dst[e];
  float ds = 1.0f / sqrtf(deg[s] + 1.0f);
  atomicAdd(&agg1[d * INCH + c], x[s * INCH + c] * ds);
}

// h1 = relu( ((agg1 + x*dis)*dis) @ W1 + b1 )
__global__ __launch_bounds__(128) void k_gemm1(const float* __restrict__ agg1,
    const float* __restrict__ x, const float* __restrict__ deg,
    const float* __restrict__ W1, const float* __restrict__ b1, float* __restrict__ h1) {
  __shared__ float a1[INCH];
  int n = blockIdx.x, j = threadIdx.x;
  if (j < INCH) {
    float dn = 1.0f / sqrtf(deg[n] + 1.0f);
    a1[j] = (agg1[n * INCH + j] + x[n * INCH + j] * dn) * dn;
  }
  __syncthreads();
  float acc = b1[j];
#pragma unroll
  for (int c = 0; c < INCH; c++) acc += a1[c] * W1[c * HID + j];
  h1[(size_t)n * HID + j] = fmaxf(acc, 0.f);
}

// kNN k=4 per graph on h1[:, :3].
// One wave per 4 rows: 64 lanes scan strided candidates keeping branchless
// per-lane top-4, then 4 rounds of wave-wide lexicographic argmin-pop.
// Ordering matches jax.lax.top_k: ascending (d2, index).
__global__ __launch_bounds__(256) void k_knn(const float* __restrict__ h1, int* __restrict__ nbr) {
  __shared__ float cx[NN], cy[NN], cz[NN];   // 24KB
  int g = blockIdx.y, tid = threadIdx.x;
  for (int i = tid; i < NN; i += 256) {
    const float* r = h1 + (size_t)(g * NN + i) * HID;
    cx[i] = r[0]; cy[i] = r[1]; cz[i] = r[2];
  }
  __syncthreads();
  int wid = tid >> 6, lane = tid & 63;
  int row0 = blockIdx.x * 16 + wid * 4;
  float mx[4], my[4], mz[4];
#pragma unroll
  for (int r = 0; r < 4; r++) { mx[r] = cx[row0 + r]; my[r] = cy[row0 + r]; mz[r] = cz[row0 + r]; }
  float t0[4], t1[4], t2[4], t3[4];
  int   i0[4], i1[4], i2[4], i3[4];
#pragma unroll
  for (int r = 0; r < 4; r++) {
    t0[r] = t1[r] = t2[r] = t3[r] = 3e38f;
    i0[r] = i1[r] = i2[r] = i3[r] = 0x7fffffff;
  }
  for (int i = 0; i < 32; i++) {
    int j = i * 64 + lane;
    float px = cx[j], py = cy[j], pz = cz[j];
#pragma unroll
    for (int r = 0; r < 4; r++) {
      float dx = px - mx[r], dy = py - my[r], dz = pz - mz[r];
      float d2 = dx * dx + dy * dy + dz * dz;
      if (j == row0 + r) d2 = 3e38f;   // exclude self
      bool in3 = d2 < t3[r], in2 = d2 < t2[r], in1 = d2 < t1[r], in0 = d2 < t0[r];
      t3[r] = in2 ? t2[r] : (in3 ? d2 : t3[r]); i3[r] = in2 ? i2[r] : (in3 ? j : i3[r]);
      t2[r] = in1 ? t1[r] : (in2 ? d2 : t2[r]); i2[r] = in1 ? i1[r] : (in2 ? j : i2[r]);
      t1[r] = in0 ? t0[r] : (in1 ? d2 : t1[r]); i1[r] = in0 ? i0[r] : (in1 ? j : i1[r]);
      t0[r] = in0 ? d2 : t0[r];                 i0[r] = in0 ? j : i0[r];
    }
  }
#pragma unroll
  for (int r = 0; r < 4; r++) {
    float a0 = t0[r], a1 = t1[r], a2 = t2[r], a3 = t3[r];
    int   b0 = i0[r], b1 = i1[r], b2 = i2[r], b3 = i3[r];
    int p = 0;
    int r0 = 0, r1 = 0, r2 = 0, r3 = 0;
#pragma unroll
    for (int k = 0; k < 4; k++) {
      float cd = (p == 0) ? a0 : (p == 1) ? a1 : (p == 2) ? a2 : (p == 3) ? a3 : 3e38f;
      int   ci = (p == 0) ? b0 : (p == 1) ? b1 : (p == 2) ? b2 : (p == 3) ? b3 : 0x7fffffff;
      float wd = cd; int wi = ci;
#pragma unroll
      for (int off = 32; off; off >>= 1) {
        float od = __shfl_xor(wd, off, 64);
        int   oi = __shfl_xor(wi, off, 64);
        bool take = (od < wd) || (od == wd && oi < wi);
        wd = take ? od : wd; wi = take ? oi : wi;
      }
      if (k == 0) r0 = wi; else if (k == 1) r1 = wi; else if (k == 2) r2 = wi; else r3 = wi;
      if (ci == wi) p++;    // owner pops (indices unique)
    }
    if (lane == 0) {
      int node = g * NN + row0 + r;
      ((int4*)nbr)[node] = make_int4(g * NN + r0, g * NN + r1, g * NN + r2, g * NN + r3);
    }
  }
}

// agg2[n] = (h1[n] + sum_{4 nbrs} h1[nbr]) * (1/5)
__global__ void k_agg2(const float* __restrict__ h1, const int* __restrict__ nbr,
                       float* __restrict__ agg2) {
  int t = blockIdx.x * 256 + threadIdx.x;   // NT*HID threads
  int n = t >> 7, cc = t & 127;
  const int4 nb = ((const int4*)nbr)[n];
  const float nrm = 0.2f;
  float v = h1[(size_t)n * HID + cc]
          + h1[(size_t)nb.x * HID + cc] + h1[(size_t)nb.y * HID + cc]
          + h1[(size_t)nb.z * HID + cc] + h1[(size_t)nb.w * HID + cc];
  agg2[t] = v * nrm;
}

// h2 = relu(agg2 @ W2 + b2), tiled 64x128 output per block
__global__ __launch_bounds__(256) void k_gemm2(const float* __restrict__ A,
    const float* __restrict__ W2, const float* __restrict__ b2, float* __restrict__ h2) {
  __shared__ float At[64][17];
  __shared__ float Bt[16 * 128];
  int tid = threadIdx.x;
  int rbase = blockIdx.x * 64;
  int rg = tid >> 5;            // 0..7 -> rows rg*8..+8
  int cg = (tid & 31) * 4;      // cols
  float acc[8][4];
#pragma unroll
  for (int i = 0; i < 8; i++)
#pragma unroll
    for (int j = 0; j < 4; j++) acc[i][j] = 0.f;
  for (int k0 = 0; k0 < HID; k0 += 16) {
    {
      int r = tid >> 2;
      int kk = (tid & 3) * 4;
      float4 v = *(const float4*)&A[(size_t)(rbase + r) * HID + k0 + kk];
      At[r][kk] = v.x; At[r][kk + 1] = v.y; At[r][kk + 2] = v.z; At[r][kk + 3] = v.w;
    }
    {
      int kk = tid >> 5;
      int cc = (tid & 31) * 4;
      *(float4*)&Bt[kk * 128 + cc] = *(const float4*)&W2[(k0 + kk) * HID + cc];
      *(float4*)&Bt[(kk + 8) * 128 + cc] = *(const float4*)&W2[(k0 + kk + 8) * HID + cc];
    }
    __syncthreads();
#pragma unroll
    for (int kk = 0; kk < 16; kk++) {
      float4 bv = *(const float4*)&Bt[kk * 128 + cg];
#pragma unroll
      for (int i = 0; i < 8; i++) {
        float av = At[rg * 8 + i][kk];
        acc[i][0] += av * bv.x; acc[i][1] += av * bv.y;
        acc[i][2] += av * bv.z; acc[i][3] += av * bv.w;
      }
    }
    __syncthreads();
  }
#pragma unroll
  for (int i = 0; i < 8; i++) {
    int r = rbase + rg * 8 + i;
#pragma unroll
    for (int j = 0; j < 4; j++) {
      float v = acc[i][j] + b2[cg + j];
      h2[(size_t)r * HID + cg + j] = fmaxf(v, 0.f);
    }
  }
}

// s = softmax(h2 @ Wp + bp) over C=64; 4 waves/block share the Wp LDS copy,
// each wave handles 16 nodes (one node per iteration, one lane per cluster).
__global__ __launch_bounds__(256) void k_s(const float* __restrict__ h2,
    const float* __restrict__ Wp, const float* __restrict__ bp, float* __restrict__ s_out) {
  __shared__ float wp[HID * CL];     // 32KB
  __shared__ float hrow[4][HID];     // 2KB
  int tid = threadIdx.x, wid = tid >> 6, lane = tid & 63;
  {
    const float4* wp4 = (const float4*)Wp;
    float4* wps = (float4*)wp;
    for (int i = tid; i < HID * CL / 4; i += 256) wps[i] = wp4[i];
  }
  __syncthreads();
  float bpv = bp[lane];
  for (int u = 0; u < 16; u++) {
    int n = blockIdx.x * 64 + wid * 16 + u;
    hrow[wid][lane]      = h2[(size_t)n * HID + lane];
    hrow[wid][lane + 64] = h2[(size_t)n * HID + lane + 64];
    __syncthreads();
    float acc = bpv;
#pragma unroll 8
    for (int k = 0; k < HID; k++) acc += hrow[wid][k] * wp[k * CL + lane];
    float m = acc;
    for (int off = 32; off; off >>= 1) m = fmaxf(m, __shfl_xor(m, off, 64));
    float e = expf(acc - m);
    float sum = e;
    for (int off = 32; off; off >>= 1) sum += __shfl_xor(sum, off, 64);
    s_out[(size_t)n * CL + lane] = e / sum;
    __syncthreads();
  }
}

// per-graph partials: ssum[c]+=s, ca[c]+=s*deg, msum+=deg
// grid (32 slices of 64 nodes, 8 graphs) — atomic-combined
__global__ __launch_bounds__(256) void k_red1(const float* __restrict__ s,
    const float* __restrict__ deg, float* __restrict__ ca, float* __restrict__ ssum,
    float* __restrict__ msum) {
  __shared__ float red[256];
  int b = blockIdx.y, sl = blockIdx.x, tid = threadIdx.x;
  int c = tid & 63, q = tid >> 6;
  float a_ss = 0, a_ca = 0, a_m = 0;
  int n0 = sl * 64;
  for (int n = n0 + q; n < n0 + 64; n += 4) {
    float sv = s[((size_t)b * NN + n) * CL + c];
    float dv = deg[b * NN + n];
    a_ss += sv; a_ca += sv * dv;
    if (c == 0) a_m += dv;
  }
  red[tid] = a_ss; __syncthreads();
  if (q == 0) atomicAdd(&ssum[b * CL + c], red[c] + red[64 + c] + red[128 + c] + red[192 + c]);
  __syncthreads();
  red[tid] = a_ca; __syncthreads();
  if (q == 0) atomicAdd(&ca[b * CL + c], red[c] + red[64 + c] + red[128 + c] + red[192 + c]);
  __syncthreads();
  red[tid] = (c == 0) ? a_m : 0.f; __syncthreads();
  if (tid == 0) atomicAdd(&msum[b], red[0] + red[64] + red[128] + red[192]);
}

// ss[b] += s_tile^T s_tile  (64-node slices, grid (32,8))
__global__ __launch_bounds__(256) void k_ss(const float* __restrict__ s, float* __restrict__ ss) {
  __shared__ float st[64 * 64];    // 16KB
  int b = blockIdx.y, sl = blockIdx.x, tid = threadIdx.x;
  const float* sp = s + ((size_t)b * NN + sl * 64) * CL;
  for (int i = tid; i < 64 * 64; i += 256) st[i] = sp[i];
  __syncthreads();
  int c = tid & 63, dg = (tid >> 6) * 16;
  float acc[16];
#pragma unroll
  for (int i = 0; i < 16; i++) acc[i] = 0.f;
  for (int n = 0; n < 64; n++) {
    float a = st[n * 64 + c];
#pragma unroll
    for (int i = 0; i < 16; i++) acc[i] += a * st[n * 64 + dg + i];
  }
  float* outp = ss + (size_t)b * CL * CL + c * CL + dg;
  for (int i = 0; i < 16; i++) atomicAdd(&outp[i], acc[i]);
}

// pool[b,c,f] += sum_n s[b,n,c]*h2[b,n,f]  (64-node slices, grid (32,8))
__global__ __launch_bounds__(256) void k_pool(const float* __restrict__ s,
    const float* __restrict__ h2, float* __restrict__ pool) {
  __shared__ float st[64 * 64];    // 16KB
  __shared__ float ht[64 * 128];   // 32KB
  int b = blockIdx.y, sl = blockIdx.x, tid = threadIdx.x;
  int c = tid & 63, fg = (tid >> 6) * 32;
  float acc[32];
#pragma unroll
  for (int i = 0; i < 32; i++) acc[i] = 0.f;
  int nb = sl * 64;
  const float* sp = s + ((size_t)b * NN + nb) * CL;
  const float* hp = h2 + ((size_t)b * NN + nb) * HID;
  for (int i = tid; i < 64 * 64; i += 256) st[i] = sp[i];
  for (int i = tid; i < 64 * 128; i += 256) ht[i] = hp[i];
  __syncthreads();
  for (int n = 0; n < 64; n++) {
    float a = st[n * 64 + c];
#pragma unroll
    for (int i = 0; i < 32; i++) acc[i] += a * ht[n * 128 + fg + i];
  }
  float* outp = pool + (size_t)b * CL * HID + c * HID + fg;
  for (int i = 0; i < 32; i++) atomicAdd(&outp[i], acc[i]);
}

// trace(s^T A s) per graph = sum over edges of dot(s[src], s[dst]).
// 16 lanes per edge, float4 per lane: one row = 256B coalesced; 4 edges/wave;
// shuffle reduce over 4 rounds (all 4 groups reduced simultaneously).
__global__ __launch_bounds__(256) void k_trace(const int* __restrict__ src,
    const int* __restrict__ dst, const float* __restrict__ s, float* __restrict__ tr) {
  __shared__ float bins[8];
  int tid = threadIdx.x;
  if (tid < 8) bins[tid] = 0.f;
  __syncthreads();
  int sub = tid & 15;
  int grp = (blockIdx.x * 256 + tid) >> 4;   // 8192 groups
  const float4* s4 = (const float4*)s;
  for (int e = grp; e < NE; e += 8192) {
    int se = src[e], de = dst[e];
    float4 a = s4[se * 16 + sub];
    float4 b = s4[de * 16 + sub];
    float v = a.x * b.x + a.y * b.y + a.z * b.z + a.w * b.w;
    v += __shfl_xor(v, 1, 64);
    v += __shfl_xor(v, 2, 64);
    v += __shfl_xor(v, 4, 64);
    v += __shfl_xor(v, 8, 64);
    if (sub == 0) atomicAdd(&bins[se >> 11], v);
  }
  __syncthreads();
  if (tid < 8) atomicAdd(&tr[tid], bins[tid]);
}

// selu then log_softmax over F=128; one row (b,c) per block
__global__ __launch_bounds__(128) void k_lsm(const float* __restrict__ pool, float* __restrict__ out) {
  __shared__ float r[2], r2[2];
  int row = blockIdx.x, tid = threadIdx.x;
  float v = pool[(size_t)row * HID + tid];
  const float scale = 1.0507009873554805f, alpha = 1.6732632423543772f;
  v = scale * (v > 0.f ? v : alpha * expm1f(v));
  float m = v;
  for (int off = 32; off; off >>= 1) m = fmaxf(m, __shfl_xor(m, off, 64));
  if ((tid & 63) == 0) r[tid >> 6] = m;
  __syncthreads();
  m = fmaxf(r[0], r[1]);
  float e = expf(v - m);
  float sum = e;
  for (int off = 32; off; off >>= 1) sum += __shfl_xor(sum, off, 64);
  if ((tid & 63) == 0) r2[tid >> 6] = sum;
  __syncthreads();
  sum = r2[0] + r2[1];
  out[(size_t)row * HID + tid] = v - m - logf(sum);
}

// per-graph scalar: spectral + ortho + cluster, atomic mean into outs[0]
__global__ __launch_bounds__(256) void k_scalar(const float* __restrict__ ss,
    const float* __restrict__ ca, const float* __restrict__ ssum,
    const float* __restrict__ msum, const float* __restrict__ tr, float* __restrict__ outs) {
  __shared__ float red[256];
  int tid = threadIdx.x, b = blockIdx.x;
  float loc = 0.f;
  for (int i = tid; i < 4096; i += 256) { float v = ss[b * 4096 + i]; loc += v * v; }
  red[tid] = loc; __syncthreads();
  for (int s2 = 128; s2; s2 >>= 1) { if (tid < s2) red[tid] += red[tid + s2]; __syncthreads(); }
  float fro = sqrtf(red[0]);
  __syncthreads();
  loc = 0.f;
  for (int i = tid; i < 4096; i += 256) {
    float v = ss[b * 4096 + i] / fro - (((i % 65) == 0) ? 0.125f : 0.f);
    loc += v * v;
  }
  red[tid] = loc; __syncthreads();
  for (int s2 = 128; s2; s2 >>= 1) { if (tid < s2) red[tid] += red[tid + s2]; __syncthreads(); }
  float ortho_b = sqrtf(red[0]);
  __syncthreads();
  loc = 0.f;
  if (tid < 64) { float v = ca[b * 64 + tid]; loc = v * v; }
  red[tid] = loc; __syncthreads();
  for (int s2 = 128; s2; s2 >>= 1) { if (tid < s2) red[tid] += red[tid + s2]; __syncthreads(); }
  float caSq = red[0];
  __syncthreads();
  loc = 0.f;
  if (tid < 64) { float v = ssum[b * 64 + tid]; loc = v * v; }
  red[tid] = loc; __syncthreads();
  for (int s2 = 128; s2; s2 >>= 1) { if (tid < s2) red[tid] += red[tid + s2]; __syncthreads(); }
  float ssumSq = red[0];
  __syncthreads();
  if (tid == 0) {
    float m2 = msum[b];                       // = 2*m
    float spectral_b = -(tr[b] - caSq / m2) / m2;
    float cluster_b = sqrtf(ssumSq) / 2048.0f * 8.0f - 1.0f;
    atomicAdd(&outs[0], (spectral_b + ortho_b + cluster_b) * 0.125f);
  }
}

extern "C" void kernel_launch(void* const* d_in, const int* in_sizes, int n_in,
                              void* d_out, int out_size, void* d_ws, size_t ws_size,
                              hipStream_t stream) {
  (void)in_sizes; (void)n_in; (void)out_size; (void)ws_size;
  const float* x   = (const float*)d_in[0];
  const int* esrc  = (const int*)d_in[1];
  const int* edst  = (const int*)d_in[2];
  const float* W1  = (const float*)d_in[4];
  const float* b1  = (const float*)d_in[5];
  const float* W2  = (const float*)d_in[6];
  const float* b2  = (const float*)d_in[7];
  const float* Wp  = (const float*)d_in[8];
  const float* bp  = (const float*)d_in[9];
  float* out = (float*)d_out;
  float* ws  = (float*)d_ws;

  float* deg   = ws + OFF_DEG;
  float* agg1  = ws + OFF_AGG1;
  float* h1    = ws + OFF_H1;
  int*   nbr   = (int*)(ws + OFF_NBR);
  float* agg2  = ws + OFF_AGG2;
  float* h2    = ws + OFF_H2;
  float* pool  = ws + OFF_POOL;
  float* ssb   = ws + OFF_SS;
  float* tr    = ws + OFF_TR;
  float* ca    = ws + OFF_CA;
  float* ssum  = ws + OFF_SSUM;
  float* msum  = ws + OFF_MS;
  float* s_out = out + 65537;   // chunk 2: s [8,2048,64]

  k_zero<<<(278528 + 255) / 256, 256, 0, stream>>>(ws, 278528);             // deg+agg1
  k_zero<<<(99344 + 255) / 256, 256, 0, stream>>>(ws + OFF_POOL, 99344);    // pool+ss+tr+ca+ssum+msum
  k_zero<<<1, 256, 0, stream>>>(out + 65536, 1);                            // loss accumulator
  k_deg<<<NE / 256, 256, 0, stream>>>(edst, deg);
  k_scatter1<<<NE * 16 / 256, 256, 0, stream>>>(esrc, edst, x, deg, agg1);
  k_gemm1<<<NT, 128, 0, stream>>>(agg1, x, deg, W1, b1, h1);
  k_knn<<<dim3(128, 8), 256, 0, stream>>>(h1, nbr);
  k_agg2<<<NT * HID / 256, 256, 0, stream>>>(h1, nbr, agg2);
  k_gemm2<<<NT / 64, 256, 0, stream>>>(agg2, W2, b2, h2);
  k_s<<<NT / 64, 256, 0, stream>>>(h2, Wp, bp, s_out);
  k_red1<<<dim3(32, BGR), 256, 0, stream>>>(s_out, deg, ca, ssum, msum);
  k_ss<<<dim3(32, 8), 256, 0, stream>>>(s_out, ssb);
  k_pool<<<dim3(32, 8), 256, 0, stream>>>(s_out, h2, pool);
  k_trace<<<512, 256, 0, stream>>>(esrc, edst, s_out, tr);
  k_lsm<<<512, 128, 0, stream>>>(pool, out);
  k_scalar<<<BGR, 256, 0, stream>>>(ssb, ca, ssum, msum, tr, out + 65536);
}

// Round 5
// 285.914 us; speedup vs baseline: 2.9671x; 1.5249x over previous
//
#include <hip/hip_runtime.h>
#include <math.h>

#define BGR 8
#define NN 2048
#define KNN 4
#define INCH 16
#define HID 128
#define CL 64
#define NE 262144
#define NT (BGR*NN)   // 16384

// workspace layout (float offsets)
#define OFF_DEG   0            // 16384
#define OFF_AGG1  16384        // 262144
#define OFF_H1    278528       // 2097152  (reused as part_pool after agg2)
#define OFF_NBR   2375680      // 65536 (ints)
#define OFF_AGG2  2441216      // 2097152  (reused as part_ss after gemm2)
#define OFF_H2    4538368      // 2097152
#define OFF_POOL  6635520      // 65536
#define OFF_SS    6701056      // 32768
#define OFF_TR    6733824      // 8
#define OFF_CA    6733832      // 512
#define OFF_SSUM  6734344      // 512
#define OFF_MS    6734856      // 8
// total 6734864 floats = ~27 MB

__global__ void k_zero(float* p, int n) {
  int i = blockIdx.x * 256 + threadIdx.x;
  if (i < n) p[i] = 0.f;
}

// zero tr+ca+ssum+msum (1040 contiguous floats) and the loss accumulator
__global__ void k_zero_small(float* p, float* loss) {
  int i = blockIdx.x * 256 + threadIdx.x;
  if (i < 1040) p[i] = 0.f;
  if (i == 0) loss[0] = 0.f;
}

// in-degree histogram over original edges (also = adj.sum(1) for dmon)
__global__ void k_deg(const int* __restrict__ dst, float* __restrict__ deg) {
  int e = blockIdx.x * 256 + threadIdx.x;
  if (e < NE) atomicAdd(&deg[dst[e]], 1.0f);
}

// scatter x[src]*dis[src] into agg1[dst] (16 channels, linearity of GCN)
__global__ void k_scatter1(const int* __restrict__ src, const int* __restrict__ dst,
                           const float* __restrict__ x, const float* __restrict__ deg,
                           float* __restrict__ agg1) {
  int t = blockIdx.x * 256 + threadIdx.x;
  int e = t >> 4, c = t & 15;
  if (e >= NE) return;
  int s = src[e], d = dst[e];
  float ds = 1.0f / sqrtf(deg[s] + 1.0f);
  atomicAdd(&agg1[d * INCH + c], x[s * INCH + c] * ds);
}

// h1 = relu( ((agg1 + x*dis)*dis) @ W1 + b1 )
__global__ __launch_bounds__(128) void k_gemm1(const float* __restrict__ agg1,
    const float* __restrict__ x, const float* __restrict__ deg,
    const float* __restrict__ W1, const float* __restrict__ b1, float* __restrict__ h1) {
  __shared__ float a1[INCH];
  int n = blockIdx.x, j = threadIdx.x;
  if (j < INCH) {
    float dn = 1.0f / sqrtf(deg[n] + 1.0f);
    a1[j] = (agg1[n * INCH + j] + x[n * INCH + j] * dn) * dn;
  }
  __syncthreads();
  float acc = b1[j];
#pragma unroll
  for (int c = 0; c < INCH; c++) acc += a1[c] * W1[c * HID + j];
  h1[(size_t)n * HID + j] = fmaxf(acc, 0.f);
}

// kNN k=4 per graph on h1[:, :3].
// One wave per 4 rows: 64 lanes scan strided candidates keeping branchless
// per-lane top-4, then 4 rounds of wave-wide lexicographic argmin-pop.
// Ordering matches jax.lax.top_k: ascending (d2, index).
__global__ __launch_bounds__(256) void k_knn(const float* __restrict__ h1, int* __restrict__ nbr) {
  __shared__ float cx[NN], cy[NN], cz[NN];   // 24KB
  int g = blockIdx.y, tid = threadIdx.x;
  for (int i = tid; i < NN; i += 256) {
    const float* r = h1 + (size_t)(g * NN + i) * HID;
    cx[i] = r[0]; cy[i] = r[1]; cz[i] = r[2];
  }
  __syncthreads();
  int wid = tid >> 6, lane = tid & 63;
  int row0 = blockIdx.x * 16 + wid * 4;
  float mx[4], my[4], mz[4];
#pragma unroll
  for (int r = 0; r < 4; r++) { mx[r] = cx[row0 + r]; my[r] = cy[row0 + r]; mz[r] = cz[row0 + r]; }
  float t0[4], t1[4], t2[4], t3[4];
  int   i0[4], i1[4], i2[4], i3[4];
#pragma unroll
  for (int r = 0; r < 4; r++) {
    t0[r] = t1[r] = t2[r] = t3[r] = 3e38f;
    i0[r] = i1[r] = i2[r] = i3[r] = 0x7fffffff;
  }
  for (int i = 0; i < 32; i++) {
    int j = i * 64 + lane;
    float px = cx[j], py = cy[j], pz = cz[j];
#pragma unroll
    for (int r = 0; r < 4; r++) {
      float dx = px - mx[r], dy = py - my[r], dz = pz - mz[r];
      float d2 = dx * dx + dy * dy + dz * dz;
      if (j == row0 + r) d2 = 3e38f;   // exclude self
      bool in3 = d2 < t3[r], in2 = d2 < t2[r], in1 = d2 < t1[r], in0 = d2 < t0[r];
      t3[r] = in2 ? t2[r] : (in3 ? d2 : t3[r]); i3[r] = in2 ? i2[r] : (in3 ? j : i3[r]);
      t2[r] = in1 ? t1[r] : (in2 ? d2 : t2[r]); i2[r] = in1 ? i1[r] : (in2 ? j : i2[r]);
      t1[r] = in0 ? t0[r] : (in1 ? d2 : t1[r]); i1[r] = in0 ? i0[r] : (in1 ? j : i1[r]);
      t0[r] = in0 ? d2 : t0[r];                 i0[r] = in0 ? j : i0[r];
    }
  }
#pragma unroll
  for (int r = 0; r < 4; r++) {
    float a0 = t0[r], a1 = t1[r], a2 = t2[r], a3 = t3[r];
    int   b0 = i0[r], b1 = i1[r], b2 = i2[r], b3 = i3[r];
    int p = 0;
    int r0 = 0, r1 = 0, r2 = 0, r3 = 0;
#pragma unroll
    for (int k = 0; k < 4; k++) {
      float cd = (p == 0) ? a0 : (p == 1) ? a1 : (p == 2) ? a2 : (p == 3) ? a3 : 3e38f;
      int   ci = (p == 0) ? b0 : (p == 1) ? b1 : (p == 2) ? b2 : (p == 3) ? b3 : 0x7fffffff;
      float wd = cd; int wi = ci;
#pragma unroll
      for (int off = 32; off; off >>= 1) {
        float od = __shfl_xor(wd, off, 64);
        int   oi = __shfl_xor(wi, off, 64);
        bool take = (od < wd) || (od == wd && oi < wi);
        wd = take ? od : wd; wi = take ? oi : wi;
      }
      if (k == 0) r0 = wi; else if (k == 1) r1 = wi; else if (k == 2) r2 = wi; else r3 = wi;
      if (ci == wi) p++;    // owner pops (indices unique)
    }
    if (lane == 0) {
      int node = g * NN + row0 + r;
      ((int4*)nbr)[node] = make_int4(g * NN + r0, g * NN + r1, g * NN + r2, g * NN + r3);
    }
  }
}

// agg2[n] = (h1[n] + sum_{4 nbrs} h1[nbr]) * (1/5)
__global__ void k_agg2(const float* __restrict__ h1, const int* __restrict__ nbr,
                       float* __restrict__ agg2) {
  int t = blockIdx.x * 256 + threadIdx.x;   // NT*HID threads
  int n = t >> 7, cc = t & 127;
  const int4 nb = ((const int4*)nbr)[n];
  const float nrm = 0.2f;
  float v = h1[(size_t)n * HID + cc]
          + h1[(size_t)nb.x * HID + cc] + h1[(size_t)nb.y * HID + cc]
          + h1[(size_t)nb.z * HID + cc] + h1[(size_t)nb.w * HID + cc];
  agg2[t] = v * nrm;
}

// h2 = relu(agg2 @ W2 + b2), tiled 64x128 output per block
__global__ __launch_bounds__(256) void k_gemm2(const float* __restrict__ A,
    const float* __restrict__ W2, const float* __restrict__ b2, float* __restrict__ h2) {
  __shared__ float At[64][17];
  __shared__ float Bt[16 * 128];
  int tid = threadIdx.x;
  int rbase = blockIdx.x * 64;
  int rg = tid >> 5;            // 0..7 -> rows rg*8..+8
  int cg = (tid & 31) * 4;      // cols
  float acc[8][4];
#pragma unroll
  for (int i = 0; i < 8; i++)
#pragma unroll
    for (int j = 0; j < 4; j++) acc[i][j] = 0.f;
  for (int k0 = 0; k0 < HID; k0 += 16) {
    {
      int r = tid >> 2;
      int kk = (tid & 3) * 4;
      float4 v = *(const float4*)&A[(size_t)(rbase + r) * HID + k0 + kk];
      At[r][kk] = v.x; At[r][kk + 1] = v.y; At[r][kk + 2] = v.z; At[r][kk + 3] = v.w;
    }
    {
      int kk = tid >> 5;
      int cc = (tid & 31) * 4;
      *(float4*)&Bt[kk * 128 + cc] = *(const float4*)&W2[(k0 + kk) * HID + cc];
      *(float4*)&Bt[(kk + 8) * 128 + cc] = *(const float4*)&W2[(k0 + kk + 8) * HID + cc];
    }
    __syncthreads();
#pragma unroll
    for (int kk = 0; kk < 16; kk++) {
      float4 bv = *(const float4*)&Bt[kk * 128 + cg];
#pragma unroll
      for (int i = 0; i < 8; i++) {
        float av = At[rg * 8 + i][kk];
        acc[i][0] += av * bv.x; acc[i][1] += av * bv.y;
        acc[i][2] += av * bv.z; acc[i][3] += av * bv.w;
      }
    }
    __syncthreads();
  }
#pragma unroll
  for (int i = 0; i < 8; i++) {
    int r = rbase + rg * 8 + i;
#pragma unroll
    for (int j = 0; j < 4; j++) {
      float v = acc[i][j] + b2[cg + j];
      h2[(size_t)r * HID + cg + j] = fmaxf(v, 0.f);
    }
  }
}

// s = softmax(h2 @ Wp + bp) over C=64; 4 waves/block share the Wp LDS copy,
// each wave handles 16 nodes (one node per iteration, one lane per cluster).
__global__ __launch_bounds__(256) void k_s(const float* __restrict__ h2,
    const float* __restrict__ Wp, const float* __restrict__ bp, float* __restrict__ s_out) {
  __shared__ float wp[HID * CL];     // 32KB
  __shared__ float hrow[4][HID];     // 2KB
  int tid = threadIdx.x, wid = tid >> 6, lane = tid & 63;
  {
    const float4* wp4 = (const float4*)Wp;
    float4* wps = (float4*)wp;
    for (int i = tid; i < HID * CL / 4; i += 256) wps[i] = wp4[i];
  }
  __syncthreads();
  float bpv = bp[lane];
  for (int u = 0; u < 16; u++) {
    int n = blockIdx.x * 64 + wid * 16 + u;
    hrow[wid][lane]      = h2[(size_t)n * HID + lane];
    hrow[wid][lane + 64] = h2[(size_t)n * HID + lane + 64];
    __syncthreads();
    float acc = bpv;
#pragma unroll 8
    for (int k = 0; k < HID; k++) acc += hrow[wid][k] * wp[k * CL + lane];
    float m = acc;
    for (int off = 32; off; off >>= 1) m = fmaxf(m, __shfl_xor(m, off, 64));
    float e = expf(acc - m);
    float sum = e;
    for (int off = 32; off; off >>= 1) sum += __shfl_xor(sum, off, 64);
    s_out[(size_t)n * CL + lane] = e / sum;
    __syncthreads();
  }
}

// fused DMoN reductions over a 64-node slice: pool & ss partials (plain
// stores, no atomics) + small ca/ssum/msum atomics. grid (32, 8).
__global__ __launch_bounds__(256) void k_dmon1(const float* __restrict__ s,
    const float* __restrict__ h2, const float* __restrict__ deg,
    float* __restrict__ part_pool, float* __restrict__ part_ss,
    float* __restrict__ ca, float* __restrict__ ssum, float* __restrict__ msum) {
  __shared__ float st[64 * 64];    // 16KB
  __shared__ float ht[64 * 128];   // 32KB
  __shared__ float dt[64];
  __shared__ float red[256];
  int b = blockIdx.y, sl = blockIdx.x, tid = threadIdx.x;
  int nb = sl * 64;
  const float* sp = s + ((size_t)b * NN + nb) * CL;
  const float* hp = h2 + ((size_t)b * NN + nb) * HID;
  for (int i = tid; i < 64 * 64 / 4; i += 256) ((float4*)st)[i] = ((const float4*)sp)[i];
  for (int i = tid; i < 64 * 128 / 4; i += 256) ((float4*)ht)[i] = ((const float4*)hp)[i];
  if (tid < 64) dt[tid] = deg[b * NN + nb + tid];
  __syncthreads();
  int c = tid & 63;
  // pool partial (64x128): per-thread 32 cols of f
  int fg = (tid >> 6) * 32;
  float acc[32];
#pragma unroll
  for (int i = 0; i < 32; i++) acc[i] = 0.f;
  for (int n = 0; n < 64; n++) {
    float a = st[n * 64 + c];
#pragma unroll
    for (int i = 0; i < 32; i++) acc[i] += a * ht[n * 128 + fg + i];
  }
  float* pp = part_pool + ((size_t)(b * 32 + sl)) * 8192 + c * 128 + fg;
#pragma unroll
  for (int i = 0; i < 32; i += 4)
    *(float4*)&pp[i] = make_float4(acc[i], acc[i + 1], acc[i + 2], acc[i + 3]);
  // ss partial (64x64): per-thread 16 cols
  int dg = (tid >> 6) * 16;
  float sacc[16];
#pragma unroll
  for (int i = 0; i < 16; i++) sacc[i] = 0.f;
  for (int n = 0; n < 64; n++) {
    float a = st[n * 64 + c];
#pragma unroll
    for (int i = 0; i < 16; i++) sacc[i] += a * st[n * 64 + dg + i];
  }
  float* ps = part_ss + ((size_t)(b * 32 + sl)) * 4096 + c * 64 + dg;
#pragma unroll
  for (int i = 0; i < 16; i += 4)
    *(float4*)&ps[i] = make_float4(sacc[i], sacc[i + 1], sacc[i + 2], sacc[i + 3]);
  // ssum/ca/msum partials (small atomics)
  int q = tid >> 6;
  float a_ss = 0, a_ca = 0, a_m = 0;
  for (int n = q; n < 64; n += 4) {
    float sv = st[n * 64 + c];
    float dv = dt[n];
    a_ss += sv; a_ca += sv * dv;
    if (c == 0) a_m += dv;
  }
  red[tid] = a_ss; __syncthreads();
  if (q == 0) atomicAdd(&ssum[b * CL + c], red[c] + red[64 + c] + red[128 + c] + red[192 + c]);
  __syncthreads();
  red[tid] = a_ca; __syncthreads();
  if (q == 0) atomicAdd(&ca[b * CL + c], red[c] + red[64 + c] + red[128 + c] + red[192 + c]);
  __syncthreads();
  red[tid] = (c == 0) ? a_m : 0.f; __syncthreads();
  if (tid == 0) atomicAdd(&msum[b], red[0] + red[64] + red[128] + red[192]);
}

// fold 32 slice-partials into final pool (8x64x128) and ss (8x64x64)
__global__ void k_reduce(const float* __restrict__ part_pool,
    const float* __restrict__ part_ss, float* __restrict__ pool, float* __restrict__ ss) {
  int i = blockIdx.x * 256 + threadIdx.x;   // 0..98303
  if (i < 65536) {
    int b = i >> 13, off = i & 8191;
    const float* p = part_pool + ((size_t)b * 32) * 8192 + off;
    float v = 0.f;
#pragma unroll
    for (int k = 0; k < 32; k++) v += p[k * 8192];
    pool[i] = v;
  } else if (i < 98304) {
    int j = i - 65536;
    int b = j >> 12, off = j & 4095;
    const float* p = part_ss + ((size_t)b * 32) * 4096 + off;
    float v = 0.f;
#pragma unroll
    for (int k = 0; k < 32; k++) v += p[k * 4096];
    ss[j] = v;
  }
}

// trace(s^T A s) per graph = sum over edges of dot(s[src], s[dst]).
// 16 lanes per edge, float4 per lane: one row = 256B coalesced; 4 edges/wave;
// shuffle reduce over 4 rounds (all 4 groups reduced simultaneously).
__global__ __launch_bounds__(256) void k_trace(const int* __restrict__ src,
    const int* __restrict__ dst, const float* __restrict__ s, float* __restrict__ tr) {
  __shared__ float bins[8];
  int tid = threadIdx.x;
  if (tid < 8) bins[tid] = 0.f;
  __syncthreads();
  int sub = tid & 15;
  int grp = (blockIdx.x * 256 + tid) >> 4;   // 8192 groups
  const float4* s4 = (const float4*)s;
  for (int e = grp; e < NE; e += 8192) {
    int se = src[e], de = dst[e];
    float4 a = s4[se * 16 + sub];
    float4 b = s4[de * 16 + sub];
    float v = a.x * b.x + a.y * b.y + a.z * b.z + a.w * b.w;
    v += __shfl_xor(v, 1, 64);
    v += __shfl_xor(v, 2, 64);
    v += __shfl_xor(v, 4, 64);
    v += __shfl_xor(v, 8, 64);
    if (sub == 0) atomicAdd(&bins[se >> 11], v);
  }
  __syncthreads();
  if (tid < 8) atomicAdd(&tr[tid], bins[tid]);
}

// selu then log_softmax over F=128; one row (b,c) per block
__global__ __launch_bounds__(128) void k_lsm(const float* __restrict__ pool, float* __restrict__ out) {
  __shared__ float r[2], r2[2];
  int row = blockIdx.x, tid = threadIdx.x;
  float v = pool[(size_t)row * HID + tid];
  const float scale = 1.0507009873554805f, alpha = 1.6732632423543772f;
  v = scale * (v > 0.f ? v : alpha * expm1f(v));
  float m = v;
  for (int off = 32; off; off >>= 1) m = fmaxf(m, __shfl_xor(m, off, 64));
  if ((tid & 63) == 0) r[tid >> 6] = m;
  __syncthreads();
  m = fmaxf(r[0], r[1]);
  float e = expf(v - m);
  float sum = e;
  for (int off = 32; off; off >>= 1) sum += __shfl_xor(sum, off, 64);
  if ((tid & 63) == 0) r2[tid >> 6] = sum;
  __syncthreads();
  sum = r2[0] + r2[1];
  out[(size_t)row * HID + tid] = v - m - logf(sum);
}

// per-graph scalar: spectral + ortho + cluster, atomic mean into outs[0]
__global__ __launch_bounds__(256) void k_scalar(const float* __restrict__ ss,
    const float* __restrict__ ca, const float* __restrict__ ssum,
    const float* __restrict__ msum, const float* __restrict__ tr, float* __restrict__ outs) {
  __shared__ float red[256];
  int tid = threadIdx.x, b = blockIdx.x;
  float loc = 0.f;
  for (int i = tid; i < 4096; i += 256) { float v = ss[b * 4096 + i]; loc += v * v; }
  red[tid] = loc; __syncthreads();
  for (int s2 = 128; s2; s2 >>= 1) { if (tid < s2) red[tid] += red[tid + s2]; __syncthreads(); }
  float fro = sqrtf(red[0]);
  __syncthreads();
  loc = 0.f;
  for (int i = tid; i < 4096; i += 256) {
    float v = ss[b * 4096 + i] / fro - (((i % 65) == 0) ? 0.125f : 0.f);
    loc += v * v;
  }
  red[tid] = loc; __syncthreads();
  for (int s2 = 128; s2; s2 >>= 1) { if (tid < s2) red[tid] += red[tid + s2]; __syncthreads(); }
  float ortho_b = sqrtf(red[0]);
  __syncthreads();
  loc = 0.f;
  if (tid < 64) { float v = ca[b * 64 + tid]; loc = v * v; }
  red[tid] = loc; __syncthreads();
  for (int s2 = 128; s2; s2 >>= 1) { if (tid < s2) red[tid] += red[tid + s2]; __syncthreads(); }
  float caSq = red[0];
  __syncthreads();
  loc = 0.f;
  if (tid < 64) { float v = ssum[b * 64 + tid]; loc = v * v; }
  red[tid] = loc; __syncthreads();
  for (int s2 = 128; s2; s2 >>= 1) { if (tid < s2) red[tid] += red[tid + s2]; __syncthreads(); }
  float ssumSq = red[0];
  __syncthreads();
  if (tid == 0) {
    float m2 = msum[b];                       // = 2*m
    float spectral_b = -(tr[b] - caSq / m2) / m2;
    float cluster_b = sqrtf(ssumSq) / 2048.0f * 8.0f - 1.0f;
    atomicAdd(&outs[0], (spectral_b + ortho_b + cluster_b) * 0.125f);
  }
}

extern "C" void kernel_launch(void* const* d_in, const int* in_sizes, int n_in,
                              void* d_out, int out_size, void* d_ws, size_t ws_size,
                              hipStream_t stream) {
  (void)in_sizes; (void)n_in; (void)out_size; (void)ws_size;
  const float* x   = (const float*)d_in[0];
  const int* esrc  = (const int*)d_in[1];
  const int* edst  = (const int*)d_in[2];
  const float* W1  = (const float*)d_in[4];
  const float* b1  = (const float*)d_in[5];
  const float* W2  = (const float*)d_in[6];
  const float* b2  = (const float*)d_in[7];
  const float* Wp  = (const float*)d_in[8];
  const float* bp  = (const float*)d_in[9];
  float* out = (float*)d_out;
  float* ws  = (float*)d_ws;

  float* deg   = ws + OFF_DEG;
  float* agg1  = ws + OFF_AGG1;
  float* h1    = ws + OFF_H1;
  int*   nbr   = (int*)(ws + OFF_NBR);
  float* agg2  = ws + OFF_AGG2;
  float* h2    = ws + OFF_H2;
  float* pool  = ws + OFF_POOL;
  float* ssb   = ws + OFF_SS;
  float* tr    = ws + OFF_TR;
  float* ca    = ws + OFF_CA;
  float* ssum  = ws + OFF_SSUM;
  float* msum  = ws + OFF_MS;
  float* part_pool = ws + OFF_H1;    // h1 dead after k_agg2
  float* part_ss   = ws + OFF_AGG2;  // agg2 dead after k_gemm2
  float* s_out = out + 65537;   // chunk 2: s [8,2048,64]

  k_zero<<<(278528 + 255) / 256, 256, 0, stream>>>(ws, 278528);             // deg+agg1
  k_zero_small<<<5, 256, 0, stream>>>(ws + OFF_TR, out + 65536);            // tr+ca+ssum+msum+loss
  k_deg<<<NE / 256, 256, 0, stream>>>(edst, deg);
  k_scatter1<<<NE * 16 / 256, 256, 0, stream>>>(esrc, edst, x, deg, agg1);
  k_gemm1<<<NT, 128, 0, stream>>>(agg1, x, deg, W1, b1, h1);
  k_knn<<<dim3(128, 8), 256, 0, stream>>>(h1, nbr);
  k_agg2<<<NT * HID / 256, 256, 0, stream>>>(h1, nbr, agg2);
  k_gemm2<<<NT / 64, 256, 0, stream>>>(agg2, W2, b2, h2);
  k_s<<<NT / 64, 256, 0, stream>>>(h2, Wp, bp, s_out);
  k_dmon1<<<dim3(32, BGR), 256, 0, stream>>>(s_out, h2, deg, part_pool, part_ss, ca, ssum, msum);
  k_reduce<<<384, 256, 0, stream>>>(part_pool, part_ss, pool, ssb);
  k_trace<<<512, 256, 0, stream>>>(esrc, edst, s_out, tr);
  k_lsm<<<512, 128, 0, stream>>>(pool, out);
  k_scalar<<<BGR, 256, 0, stream>>>(ssb, ca, ssum, msum, tr, out + 65536);
}

// Round 6
// 273.464 us; speedup vs baseline: 3.1022x; 1.0455x over previous
//
#include <hip/hip_runtime.h>
#include <math.h>

#define BGR 8
#define NN 2048
#define KNN 4
#define INCH 16
#define HID 128
#define CL 64
#define NE 262144
#define NT (BGR*NN)   // 16384

// workspace layout (float offsets)
#define OFF_DEG   0            // 16384
#define OFF_AGG1  16384        // 262144
#define OFF_H1    278528       // 2097152  (reused as part_pool after agg2)
#define OFF_NBR   2375680      // 65536 (ints)
#define OFF_AGG2  2441216      // 2097152  (reused as part_ss after gemm2)
#define OFF_H2    4538368      // 2097152
#define OFF_POOL  6635520      // 65536
#define OFF_SS    6701056      // 32768
#define OFF_TR    6733824      // 8
#define OFF_CA    6733832      // 512
#define OFF_SSUM  6734344      // 512
#define OFF_MS    6734856      // 8
// total 6734864 floats = ~27 MB

__global__ void k_zero(float* p, int n) {
  int i = blockIdx.x * 256 + threadIdx.x;
  if (i < n) p[i] = 0.f;
}

// zero tr+ca+ssum+msum (1040 contiguous floats) and the loss accumulator
__global__ void k_zero_small(float* p, float* loss) {
  int i = blockIdx.x * 256 + threadIdx.x;
  if (i < 1040) p[i] = 0.f;
  if (i == 0) loss[0] = 0.f;
}

// in-degree histogram over original edges (also = adj.sum(1) for dmon)
__global__ void k_deg(const int* __restrict__ dst, float* __restrict__ deg) {
  int e = blockIdx.x * 256 + threadIdx.x;
  if (e < NE) atomicAdd(&deg[dst[e]], 1.0f);
}

// scatter x[src]*dis[src] into agg1[dst] (16 channels, linearity of GCN)
__global__ void k_scatter1(const int* __restrict__ src, const int* __restrict__ dst,
                           const float* __restrict__ x, const float* __restrict__ deg,
                           float* __restrict__ agg1) {
  int t = blockIdx.x * 256 + threadIdx.x;
  int e = t >> 4, c = t & 15;
  if (e >= NE) return;
  int s = src[e], d = dst[e];
  float ds = 1.0f / sqrtf(deg[s] + 1.0f);
  atomicAdd(&agg1[d * INCH + c], x[s * INCH + c] * ds);
}

// h1 = relu( ((agg1 + x*dis)*dis) @ W1 + b1 )
__global__ __launch_bounds__(128) void k_gemm1(const float* __restrict__ agg1,
    const float* __restrict__ x, const float* __restrict__ deg,
    const float* __restrict__ W1, const float* __restrict__ b1, float* __restrict__ h1) {
  __shared__ float a1[INCH];
  int n = blockIdx.x, j = threadIdx.x;
  if (j < INCH) {
    float dn = 1.0f / sqrtf(deg[n] + 1.0f);
    a1[j] = (agg1[n * INCH + j] + x[n * INCH + j] * dn) * dn;
  }
  __syncthreads();
  float acc = b1[j];
#pragma unroll
  for (int c = 0; c < INCH; c++) acc += a1[c] * W1[c * HID + j];
  h1[(size_t)n * HID + j] = fmaxf(acc, 0.f);
}

// kNN k=4 per graph on h1[:, :3].
// 2 rows per wave: 64 lanes scan strided candidates keeping branchless
// per-lane top-4, then 4 rounds of wave-wide lexicographic argmin-pop.
// Ordering matches jax.lax.top_k: ascending (d2, index).
__global__ __launch_bounds__(256) void k_knn(const float* __restrict__ h1, int* __restrict__ nbr) {
  __shared__ float cx[NN], cy[NN], cz[NN];   // 24KB
  int g = blockIdx.y, tid = threadIdx.x;
  for (int i = tid; i < NN; i += 256) {
    const float* r = h1 + (size_t)(g * NN + i) * HID;
    cx[i] = r[0]; cy[i] = r[1]; cz[i] = r[2];
  }
  __syncthreads();
  int wid = tid >> 6, lane = tid & 63;
  int row0 = blockIdx.x * 8 + wid * 2;
  float mx[2], my[2], mz[2];
#pragma unroll
  for (int r = 0; r < 2; r++) { mx[r] = cx[row0 + r]; my[r] = cy[row0 + r]; mz[r] = cz[row0 + r]; }
  float t0[2], t1[2], t2[2], t3[2];
  int   i0[2], i1[2], i2[2], i3[2];
#pragma unroll
  for (int r = 0; r < 2; r++) {
    t0[r] = t1[r] = t2[r] = t3[r] = 3e38f;
    i0[r] = i1[r] = i2[r] = i3[r] = 0x7fffffff;
  }
  for (int i = 0; i < 32; i++) {
    int j = i * 64 + lane;
    float px = cx[j], py = cy[j], pz = cz[j];
#pragma unroll
    for (int r = 0; r < 2; r++) {
      float dx = px - mx[r], dy = py - my[r], dz = pz - mz[r];
      float d2 = dx * dx + dy * dy + dz * dz;
      if (j == row0 + r) d2 = 3e38f;   // exclude self
      bool in3 = d2 < t3[r], in2 = d2 < t2[r], in1 = d2 < t1[r], in0 = d2 < t0[r];
      t3[r] = in2 ? t2[r] : (in3 ? d2 : t3[r]); i3[r] = in2 ? i2[r] : (in3 ? j : i3[r]);
      t2[r] = in1 ? t1[r] : (in2 ? d2 : t2[r]); i2[r] = in1 ? i1[r] : (in2 ? j : i2[r]);
      t1[r] = in0 ? t0[r] : (in1 ? d2 : t1[r]); i1[r] = in0 ? i0[r] : (in1 ? j : i1[r]);
      t0[r] = in0 ? d2 : t0[r];                 i0[r] = in0 ? j : i0[r];
    }
  }
#pragma unroll
  for (int r = 0; r < 2; r++) {
    float a0 = t0[r], a1 = t1[r], a2 = t2[r], a3 = t3[r];
    int   b0 = i0[r], b1 = i1[r], b2 = i2[r], b3 = i3[r];
    int p = 0;
    int r0 = 0, r1 = 0, r2 = 0, r3 = 0;
#pragma unroll
    for (int k = 0; k < 4; k++) {
      float cd = (p == 0) ? a0 : (p == 1) ? a1 : (p == 2) ? a2 : (p == 3) ? a3 : 3e38f;
      int   ci = (p == 0) ? b0 : (p == 1) ? b1 : (p == 2) ? b2 : (p == 3) ? b3 : 0x7fffffff;
      float wd = cd; int wi = ci;
#pragma unroll
      for (int off = 32; off; off >>= 1) {
        float od = __shfl_xor(wd, off, 64);
        int   oi = __shfl_xor(wi, off, 64);
        bool take = (od < wd) || (od == wd && oi < wi);
        wd = take ? od : wd; wi = take ? oi : wi;
      }
      if (k == 0) r0 = wi; else if (k == 1) r1 = wi; else if (k == 2) r2 = wi; else r3 = wi;
      if (ci == wi) p++;    // owner pops (indices unique)
    }
    if (lane == 0) {
      int node = g * NN + row0 + r;
      ((int4*)nbr)[node] = make_int4(g * NN + r0, g * NN + r1, g * NN + r2, g * NN + r3);
    }
  }
}

// agg2[n] = (h1[n] + sum_{4 nbrs} h1[nbr]) * (1/5), float4 per thread
__global__ void k_agg2(const float* __restrict__ h1, const int* __restrict__ nbr,
                       float* __restrict__ agg2) {
  int t = blockIdx.x * 256 + threadIdx.x;   // NT*32 threads
  int n = t >> 5, q = t & 31;
  const int4 nb = ((const int4*)nbr)[n];
  const float4* h4 = (const float4*)h1;
  float4 a = h4[(size_t)n * 32 + q];
  float4 b = h4[(size_t)nb.x * 32 + q];
  float4 c = h4[(size_t)nb.y * 32 + q];
  float4 d = h4[(size_t)nb.z * 32 + q];
  float4 e = h4[(size_t)nb.w * 32 + q];
  float4 v = make_float4((a.x + b.x + c.x + d.x + e.x) * 0.2f,
                         (a.y + b.y + c.y + d.y + e.y) * 0.2f,
                         (a.z + b.z + c.z + d.z + e.z) * 0.2f,
                         (a.w + b.w + c.w + d.w + e.w) * 0.2f);
  ((float4*)agg2)[t] = v;
}

// h2 = relu(agg2 @ W2 + b2), tiled 64x128 output per block
__global__ __launch_bounds__(256) void k_gemm2(const float* __restrict__ A,
    const float* __restrict__ W2, const float* __restrict__ b2, float* __restrict__ h2) {
  __shared__ float At[64][17];
  __shared__ float Bt[16 * 128];
  int tid = threadIdx.x;
  int rbase = blockIdx.x * 64;
  int rg = tid >> 5;            // 0..7 -> rows rg*8..+8
  int cg = (tid & 31) * 4;      // cols
  float acc[8][4];
#pragma unroll
  for (int i = 0; i < 8; i++)
#pragma unroll
    for (int j = 0; j < 4; j++) acc[i][j] = 0.f;
  for (int k0 = 0; k0 < HID; k0 += 16) {
    {
      int r = tid >> 2;
      int kk = (tid & 3) * 4;
      float4 v = *(const float4*)&A[(size_t)(rbase + r) * HID + k0 + kk];
      At[r][kk] = v.x; At[r][kk + 1] = v.y; At[r][kk + 2] = v.z; At[r][kk + 3] = v.w;
    }
    {
      int kk = tid >> 5;
      int cc = (tid & 31) * 4;
      *(float4*)&Bt[kk * 128 + cc] = *(const float4*)&W2[(k0 + kk) * HID + cc];
      *(float4*)&Bt[(kk + 8) * 128 + cc] = *(const float4*)&W2[(k0 + kk + 8) * HID + cc];
    }
    __syncthreads();
#pragma unroll
    for (int kk = 0; kk < 16; kk++) {
      float4 bv = *(const float4*)&Bt[kk * 128 + cg];
#pragma unroll
      for (int i = 0; i < 8; i++) {
        float av = At[rg * 8 + i][kk];
        acc[i][0] += av * bv.x; acc[i][1] += av * bv.y;
        acc[i][2] += av * bv.z; acc[i][3] += av * bv.w;
      }
    }
    __syncthreads();
  }
#pragma unroll
  for (int i = 0; i < 8; i++) {
    int r = rbase + rg * 8 + i;
#pragma unroll
    for (int j = 0; j < 4; j++) {
      float v = acc[i][j] + b2[cg + j];
      h2[(size_t)r * HID + cg + j] = fmaxf(v, 0.f);
    }
  }
}

// s = softmax(h2 @ Wp + bp) over C=64.
// Lane c register-caches Wp[:,c] (128 VGPRs, coalesced load); h2 row is read
// as wave-uniform float4 (broadcast). One wave per 8 nodes, no LDS.
__global__ __launch_bounds__(256) void k_s(const float* __restrict__ h2,
    const float* __restrict__ Wp, const float* __restrict__ bp, float* __restrict__ s_out) {
  int tid = threadIdx.x, wid = tid >> 6, lane = tid & 63;
  float w[HID];
#pragma unroll
  for (int k = 0; k < HID; k++) w[k] = Wp[k * CL + lane];   // coalesced per k
  float bpv = bp[lane];
  int nbase = blockIdx.x * 32 + wid * 8;
  for (int u = 0; u < 8; u++) {
    int n = nbase + u;
    const float4* hp = (const float4*)(h2 + (size_t)n * HID);
    float acc = bpv;
#pragma unroll
    for (int k4 = 0; k4 < 32; k4++) {
      float4 h = hp[k4];
      acc += h.x * w[k4 * 4] + h.y * w[k4 * 4 + 1] + h.z * w[k4 * 4 + 2] + h.w * w[k4 * 4 + 3];
    }
    float m = acc;
    for (int off = 32; off; off >>= 1) m = fmaxf(m, __shfl_xor(m, off, 64));
    float e = expf(acc - m);
    float sum = e;
    for (int off = 32; off; off >>= 1) sum += __shfl_xor(sum, off, 64);
    s_out[(size_t)n * CL + lane] = e / sum;
  }
}

// fused DMoN reductions over a 64-node slice: pool & ss partials (plain
// stores, no atomics) + small ca/ssum/msum atomics. grid (32, 8).
__global__ __launch_bounds__(256) void k_dmon1(const float* __restrict__ s,
    const float* __restrict__ h2, const float* __restrict__ deg,
    float* __restrict__ part_pool, float* __restrict__ part_ss,
    float* __restrict__ ca, float* __restrict__ ssum, float* __restrict__ msum) {
  __shared__ float st[64 * 64];    // 16KB
  __shared__ float ht[64 * 128];   // 32KB
  __shared__ float dt[64];
  __shared__ float red[256];
  int b = blockIdx.y, sl = blockIdx.x, tid = threadIdx.x;
  int nb = sl * 64;
  const float* sp = s + ((size_t)b * NN + nb) * CL;
  const float* hp = h2 + ((size_t)b * NN + nb) * HID;
  for (int i = tid; i < 64 * 64 / 4; i += 256) ((float4*)st)[i] = ((const float4*)sp)[i];
  for (int i = tid; i < 64 * 128 / 4; i += 256) ((float4*)ht)[i] = ((const float4*)hp)[i];
  if (tid < 64) dt[tid] = deg[b * NN + nb + tid];
  __syncthreads();
  int c = tid & 63;
  // pool partial (64x128): per-thread 32 cols of f
  int fg = (tid >> 6) * 32;
  float acc[32];
#pragma unroll
  for (int i = 0; i < 32; i++) acc[i] = 0.f;
  for (int n = 0; n < 64; n++) {
    float a = st[n * 64 + c];
#pragma unroll
    for (int i = 0; i < 32; i++) acc[i] += a * ht[n * 128 + fg + i];
  }
  float* pp = part_pool + ((size_t)(b * 32 + sl)) * 8192 + c * 128 + fg;
#pragma unroll
  for (int i = 0; i < 32; i += 4)
    *(float4*)&pp[i] = make_float4(acc[i], acc[i + 1], acc[i + 2], acc[i + 3]);
  // ss partial (64x64): per-thread 16 cols
  int dg = (tid >> 6) * 16;
  float sacc[16];
#pragma unroll
  for (int i = 0; i < 16; i++) sacc[i] = 0.f;
  for (int n = 0; n < 64; n++) {
    float a = st[n * 64 + c];
#pragma unroll
    for (int i = 0; i < 16; i++) sacc[i] += a * st[n * 64 + dg + i];
  }
  float* ps = part_ss + ((size_t)(b * 32 + sl)) * 4096 + c * 64 + dg;
#pragma unroll
  for (int i = 0; i < 16; i += 4)
    *(float4*)&ps[i] = make_float4(sacc[i], sacc[i + 1], sacc[i + 2], sacc[i + 3]);
  // ssum/ca/msum partials (small atomics)
  int q = tid >> 6;
  float a_ss = 0, a_ca = 0, a_m = 0;
  for (int n = q; n < 64; n += 4) {
    float sv = st[n * 64 + c];
    float dv = dt[n];
    a_ss += sv; a_ca += sv * dv;
    if (c == 0) a_m += dv;
  }
  red[tid] = a_ss; __syncthreads();
  if (q == 0) atomicAdd(&ssum[b * CL + c], red[c] + red[64 + c] + red[128 + c] + red[192 + c]);
  __syncthreads();
  red[tid] = a_ca; __syncthreads();
  if (q == 0) atomicAdd(&ca[b * CL + c], red[c] + red[64 + c] + red[128 + c] + red[192 + c]);
  __syncthreads();
  red[tid] = (c == 0) ? a_m : 0.f; __syncthreads();
  if (tid == 0) atomicAdd(&msum[b], red[0] + red[64] + red[128] + red[192]);
}

// fold 32 slice-partials into final pool (8x64x128) and ss (8x64x64)
__global__ void k_reduce(const float* __restrict__ part_pool,
    const float* __restrict__ part_ss, float* __restrict__ pool, float* __restrict__ ss) {
  int i = blockIdx.x * 256 + threadIdx.x;   // 0..98303
  if (i < 65536) {
    int b = i >> 13, off = i & 8191;
    const float* p = part_pool + ((size_t)b * 32) * 8192 + off;
    float v = 0.f;
#pragma unroll
    for (int k = 0; k < 32; k++) v += p[k * 8192];
    pool[i] = v;
  } else if (i < 98304) {
    int j = i - 65536;
    int b = j >> 12, off = j & 4095;
    const float* p = part_ss + ((size_t)b * 32) * 4096 + off;
    float v = 0.f;
#pragma unroll
    for (int k = 0; k < 32; k++) v += p[k * 4096];
    ss[j] = v;
  }
}

// trace(s^T A s) per graph = sum over edges of dot(s[src], s[dst]).
// 16 lanes per edge, float4 per lane: one row = 256B coalesced; 4 edges/wave;
// shuffle reduce over 4 rounds (all 4 groups reduced simultaneously).
__global__ __launch_bounds__(256) void k_trace(const int* __restrict__ src,
    const int* __restrict__ dst, const float* __restrict__ s, float* __restrict__ tr) {
  __shared__ float bins[8];
  int tid = threadIdx.x;
  if (tid < 8) bins[tid] = 0.f;
  __syncthreads();
  int sub = tid & 15;
  int grp = (blockIdx.x * 256 + tid) >> 4;   // 8192 groups
  const float4* s4 = (const float4*)s;
  for (int e = grp; e < NE; e += 8192) {
    int se = src[e], de = dst[e];
    float4 a = s4[se * 16 + sub];
    float4 b = s4[de * 16 + sub];
    float v = a.x * b.x + a.y * b.y + a.z * b.z + a.w * b.w;
    v += __shfl_xor(v, 1, 64);
    v += __shfl_xor(v, 2, 64);
    v += __shfl_xor(v, 4, 64);
    v += __shfl_xor(v, 8, 64);
    if (sub == 0) atomicAdd(&bins[se >> 11], v);
  }
  __syncthreads();
  if (tid < 8) atomicAdd(&tr[tid], bins[tid]);
}

// selu then log_softmax over F=128; one row (b,c) per block
__global__ __launch_bounds__(128) void k_lsm(const float* __restrict__ pool, float* __restrict__ out) {
  __shared__ float r[2], r2[2];
  int row = blockIdx.x, tid = threadIdx.x;
  float v = pool[(size_t)row * HID + tid];
  const float scale = 1.0507009873554805f, alpha = 1.6732632423543772f;
  v = scale * (v > 0.f ? v : alpha * expm1f(v));
  float m = v;
  for (int off = 32; off; off >>= 1) m = fmaxf(m, __shfl_xor(m, off, 64));
  if ((tid & 63) == 0) r[tid >> 6] = m;
  __syncthreads();
  m = fmaxf(r[0], r[1]);
  float e = expf(v - m);
  float sum = e;
  for (int off = 32; off; off >>= 1) sum += __shfl_xor(sum, off, 64);
  if ((tid & 63) == 0) r2[tid >> 6] = sum;
  __syncthreads();
  sum = r2[0] + r2[1];
  out[(size_t)row * HID + tid] = v - m - logf(sum);
}

// per-graph scalar: spectral + ortho + cluster, atomic mean into outs[0]
__global__ __launch_bounds__(256) void k_scalar(const float* __restrict__ ss,
    const float* __restrict__ ca, const float* __restrict__ ssum,
    const float* __restrict__ msum, const float* __restrict__ tr, float* __restrict__ outs) {
  __shared__ float red[256];
  int tid = threadIdx.x, b = blockIdx.x;
  float loc = 0.f;
  for (int i = tid; i < 4096; i += 256) { float v = ss[b * 4096 + i]; loc += v * v; }
  red[tid] = loc; __syncthreads();
  for (int s2 = 128; s2; s2 >>= 1) { if (tid < s2) red[tid] += red[tid + s2]; __syncthreads(); }
  float fro = sqrtf(red[0]);
  __syncthreads();
  loc = 0.f;
  for (int i = tid; i < 4096; i += 256) {
    float v = ss[b * 4096 + i] / fro - (((i % 65) == 0) ? 0.125f : 0.f);
    loc += v * v;
  }
  red[tid] = loc; __syncthreads();
  for (int s2 = 128; s2; s2 >>= 1) { if (tid < s2) red[tid] += red[tid + s2]; __syncthreads(); }
  float ortho_b = sqrtf(red[0]);
  __syncthreads();
  loc = 0.f;
  if (tid < 64) { float v = ca[b * 64 + tid]; loc = v * v; }
  red[tid] = loc; __syncthreads();
  for (int s2 = 128; s2; s2 >>= 1) { if (tid < s2) red[tid] += red[tid + s2]; __syncthreads(); }
  float caSq = red[0];
  __syncthreads();
  loc = 0.f;
  if (tid < 64) { float v = ssum[b * 64 + tid]; loc = v * v; }
  red[tid] = loc; __syncthreads();
  for (int s2 = 128; s2; s2 >>= 1) { if (tid < s2) red[tid] += red[tid + s2]; __syncthreads(); }
  float ssumSq = red[0];
  __syncthreads();
  if (tid == 0) {
    float m2 = msum[b];                       // = 2*m
    float spectral_b = -(tr[b] - caSq / m2) / m2;
    float cluster_b = sqrtf(ssumSq) / 2048.0f * 8.0f - 1.0f;
    atomicAdd(&outs[0], (spectral_b + ortho_b + cluster_b) * 0.125f);
  }
}

extern "C" void kernel_launch(void* const* d_in, const int* in_sizes, int n_in,
                              void* d_out, int out_size, void* d_ws, size_t ws_size,
                              hipStream_t stream) {
  (void)in_sizes; (void)n_in; (void)out_size; (void)ws_size;
  const float* x   = (const float*)d_in[0];
  const int* esrc  = (const int*)d_in[1];
  const int* edst  = (const int*)d_in[2];
  const float* W1  = (const float*)d_in[4];
  const float* b1  = (const float*)d_in[5];
  const float* W2  = (const float*)d_in[6];
  const float* b2  = (const float*)d_in[7];
  const float* Wp  = (const float*)d_in[8];
  const float* bp  = (const float*)d_in[9];
  float* out = (float*)d_out;
  float* ws  = (float*)d_ws;

  float* deg   = ws + OFF_DEG;
  float* agg1  = ws + OFF_AGG1;
  float* h1    = ws + OFF_H1;
  int*   nbr   = (int*)(ws + OFF_NBR);
  float* agg2  = ws + OFF_AGG2;
  float* h2    = ws + OFF_H2;
  float* pool  = ws + OFF_POOL;
  float* ssb   = ws + OFF_SS;
  float* tr    = ws + OFF_TR;
  float* ca    = ws + OFF_CA;
  float* ssum  = ws + OFF_SSUM;
  float* msum  = ws + OFF_MS;
  float* part_pool = ws + OFF_H1;    // h1 dead after k_agg2
  float* part_ss   = ws + OFF_AGG2;  // agg2 dead after k_gemm2
  float* s_out = out + 65537;   // chunk 2: s [8,2048,64]

  k_zero<<<(278528 + 255) / 256, 256, 0, stream>>>(ws, 278528);             // deg+agg1
  k_zero_small<<<5, 256, 0, stream>>>(ws + OFF_TR, out + 65536);            // tr+ca+ssum+msum+loss
  k_deg<<<NE / 256, 256, 0, stream>>>(edst, deg);
  k_scatter1<<<NE * 16 / 256, 256, 0, stream>>>(esrc, edst, x, deg, agg1);
  k_gemm1<<<NT, 128, 0, stream>>>(agg1, x, deg, W1, b1, h1);
  k_knn<<<dim3(256, 8), 256, 0, stream>>>(h1, nbr);
  k_agg2<<<NT * 32 / 256, 256, 0, stream>>>(h1, nbr, agg2);
  k_gemm2<<<NT / 64, 256, 0, stream>>>(agg2, W2, b2, h2);
  k_s<<<NT / 32, 256, 0, stream>>>(h2, Wp, bp, s_out);
  k_dmon1<<<dim3(32, BGR), 256, 0, stream>>>(s_out, h2, deg, part_pool, part_ss, ca, ssum, msum);
  k_reduce<<<384, 256, 0, stream>>>(part_pool, part_ss, pool, ssb);
  k_trace<<<512, 256, 0, stream>>>(esrc, edst, s_out, tr);
  k_lsm<<<512, 128, 0, stream>>>(pool, out);
  k_scalar<<<BGR, 256, 0, stream>>>(ssb, ca, ssum, msum, tr, out + 65536);
}